// Round 9
// baseline (248.018 us; speedup 1.0000x reference)
//
#include <hip/hip_runtime.h>
#include <math.h>

typedef unsigned short u16;
typedef unsigned int u32;
typedef short s16x8 __attribute__((ext_vector_type(8)));
typedef float f32x4 __attribute__((ext_vector_type(4)));

#define AS1 __attribute__((address_space(1)))
#define AS3 __attribute__((address_space(3)))

__device__ __forceinline__ float bf2f(u16 u) {
    union { u32 i; float f; } v; v.i = ((u32)u) << 16; return v.f;
}
__device__ __forceinline__ u16 f2bf(float f) {
    union { float f; u32 i; } v; v.f = f;
    u32 r = v.i + 0x7fffu + ((v.i >> 16) & 1u);
    return (u16)(r >> 16);
}
__device__ __forceinline__ void gll16(const u16* g, u16* l) {
    __builtin_amdgcn_global_load_lds((const AS1 u32*)g, (AS3 u32*)l, 16, 0, 0);
}

// ---------------------------------------------------------------------------
// prep: repack weights to B^T bf16 layouts for the MFMA GEMMs; zero norm2
// (folds the old hipMemsetAsync dispatch). wdT is TAP-MAJOR + XOR-swizzled:
//   wdT[(p*192 + o)*192 + (c ^ ((o&7)<<3))] = w_d[o][c][p]
// ---------------------------------------------------------------------------
__global__ void prep_kernel(const float* __restrict__ wd, const float* __restrict__ wqkv,
                            const float* __restrict__ wfc1, const float* __restrict__ wfc2,
                            const float* __restrict__ wp,
                            u16* __restrict__ wdT, u16* __restrict__ wkvT,
                            u16* __restrict__ wf1T, u16* __restrict__ wf2T,
                            u16* __restrict__ wpT, float* __restrict__ norm2)
{
    int i = blockIdx.x * 256 + threadIdx.x;
    if (i < 1536) norm2[i] = 0.f;           // 4 batches x 384 cols
    if (i < 331776) {                       // tap-major swizzled w_d
        int o = i / 1728, r = i % 1728;
        int p = r / 192, c = r % 192;
        int cs = c ^ ((o & 7) << 3);
        wdT[(p * 192 + o) * 192 + cs] = f2bf(wd[(o * 192 + c) * 9 + p]);
    }
    if (i < 73728) {                        // rows C..3C of w_qkv (k,v only)
        int o = i / 192, c = i % 192;
        wkvT[i] = f2bf(wqkv[(192 + o) * 192 + c]);
    }
    if (i < 147456) {
        int n = i / 192, c = i % 192;       // w_fc1 (192,768) -> [768][192]
        wf1T[i] = f2bf(wfc1[c * 768 + n]);
        int n2 = i / 768, hh = i % 768;     // w_fc2 (768,192) -> [192][768]
        wf2T[i] = f2bf(wfc2[hh * 192 + n2]);
    }
    if (i < 31104) {                        // w_pT[n][p*192+c] = w_p[n][c][p], pad to 32 rows
        int n = i / 1728, r = i % 1728;
        int p = r / 192, c = r % 192;
        wpT[i] = f2bf(wp[(n * 192 + c) * 9 + p]);
    } else if (i < 55296) {
        wpT[i] = 0;
    }
}

// ---------------------------------------------------------------------------
// LN1: x NCHW fp32 -> xn token-major bf16 [16384][192]; x read once (LDS stage)
// ---------------------------------------------------------------------------
__global__ __launch_bounds__(256) void ln1_kernel(const float* __restrict__ x,
                                                  const float* __restrict__ g,
                                                  const float* __restrict__ be,
                                                  u16* __restrict__ xn)
{
    __shared__ float red0[256], red1[256];
    __shared__ float mu_s[64], rs_s[64];
    __shared__ float xt[64 * 193];          // fp32 stage, stride 193 = conflict-free
    __shared__ u16 tile[64 * 194];          // bf16 out, stride 194 (97 dwords)
    int t = threadIdx.x, tl = t & 63, cg = t >> 6;
    int m0 = blockIdx.x * 64;
    int b = m0 >> 12, hw0 = m0 & 4095;
    const float* xb = x + (size_t)b * 786432 + hw0 + tl;
    float s = 0.f, s2 = 0.f;
    for (int cc = cg; cc < 192; cc += 4) {
        float v = xb[cc * 4096];
        xt[tl * 193 + cc] = v;
        s += v; s2 += v * v;
    }
    red0[t] = s; red1[t] = s2;
    __syncthreads();
    if (t < 64) {
        float a = red0[t] + red0[64 + t] + red0[128 + t] + red0[192 + t];
        float q = red1[t] + red1[64 + t] + red1[128 + t] + red1[192 + t];
        float mu = a * (1.f / 192.f);
        float var = q * (1.f / 192.f) - mu * mu;
        mu_s[t] = mu; rs_s[t] = rsqrtf(var + 1e-5f);
    }
    __syncthreads();
    float mu = mu_s[tl], rs = rs_s[tl];
    for (int cc = cg; cc < 192; cc += 4) {
        float v = (xt[tl * 193 + cc] - mu) * rs * g[cc] + be[cc];
        tile[tl * 194 + cc] = f2bf(v);
    }
    __syncthreads();
    u32* dst = (u32*)(xn + (size_t)m0 * 192);
    for (int i = t; i < 64 * 96; i += 256) {
        int r = i / 96, c2 = i % 96;
        dst[i] = *(const u32*)&tile[r * 194 + c2 * 2];
    }
}

// ---------------------------------------------------------------------------
// offset conv as direct MFMA conv: one block per (b,h) row, BM=64 (w axis),
// N=32 (18 padded), K = 9 taps x 192 ch.
// 8 waves (512 thr), wave grid 4M x 2N -> 2 waves/SIMD.
// ---------------------------------------------------------------------------
__global__ __launch_bounds__(512) void offconv_kernel(const u16* __restrict__ xn,
                                                      const u16* __restrict__ wpT,
                                                      const float* __restrict__ bp,
                                                      float* __restrict__ off)
{
    __shared__ u16 As[64 * 200];            // stride 200: rows rotate 4 banks
    __shared__ u16 Bs[32 * 200];
    int bh = blockIdx.x;
    int b = bh >> 6, h = bh & 63;
    int t = threadIdx.x;
    int lane = t & 63, wv = t >> 6;
    int wm = wv & 3, wn = wv >> 2;          // 4 M-waves x 2 N-waves
    f32x4 acc;
    acc[0] = 0.f; acc[1] = 0.f; acc[2] = 0.f; acc[3] = 0.f;
    int r = t >> 3, cq = (t & 7) * 24;      // 8 threads per A row, 24 ch each
    for (int p = 0; p < 9; p++) {
        int dh = p / 3 - 1, dw = p % 3 - 1;
        int hr = h + dh, wr = r + dw;
        bool valid = (hr >= 0) && (hr < 64) && (wr >= 0) && (wr < 64);
        const u16* src = xn + ((size_t)(b * 4096 + hr * 64 + wr)) * 192 + cq;
#pragma unroll
        for (int j = 0; j < 3; j++) {
            s16x8 v = {0, 0, 0, 0, 0, 0, 0, 0};
            if (valid) v = *(const s16x8*)(src + j * 8);
            *(s16x8*)&As[r * 200 + cq + j * 8] = v;
        }
#pragma unroll
        for (int i = 0; i < 2; i++) {
            int q = t + i * 512;
            if (q < 768) {
                int n = q / 24, c8 = q % 24;
                *(s16x8*)&Bs[n * 200 + c8 * 8] =
                    *(const s16x8*)(wpT + n * 1728 + p * 192 + c8 * 8);
            }
        }
        __syncthreads();
#pragma unroll
        for (int kc = 0; kc < 6; kc++) {
            s16x8 af = *(const s16x8*)&As[(wm * 16 + (lane & 15)) * 200 + kc * 32 + (lane >> 4) * 8];
            s16x8 b0 = *(const s16x8*)&Bs[(wn * 16 + (lane & 15)) * 200 + kc * 32 + (lane >> 4) * 8];
            acc = __builtin_amdgcn_mfma_f32_16x16x32_bf16(af, b0, acc, 0, 0, 0);
        }
        __syncthreads();
    }
    int col = lane & 15;
    int n = wn * 16 + col;
    int wbase = wm * 16 + (lane >> 4) * 4;
    if (n < 18) {
        float bb = bp[n];
#pragma unroll
        for (int rr = 0; rr < 4; rr++) {
            int w = wbase + rr;
            off[((size_t)(b * 4096 + h * 64 + w)) * 18 + n] = acc[rr] + bb;
        }
    }
}

// ---------------------------------------------------------------------------
// fused bilinear-gather + deform output conv GEMM. BM=64, 8 waves, B staged
// once per tap into LDS from tap-major pre-swizzled wdT. (R3 structure.)
// ---------------------------------------------------------------------------
__global__ __launch_bounds__(512, 2) void gemm_deform(const u16* __restrict__ xn,
                                                      const float* __restrict__ off,
                                                      const u16* __restrict__ wdT,
                                                      u16* __restrict__ qt)
{
    __shared__ u16 As[64 * 200];            // [token][ch], stride 200 rotates banks
    __shared__ u16 Bs[192 * 192];           // per-tap B panel, XOR-swizzled cols
    __shared__ int sidx[64][9][4];
    __shared__ float swt[64][9][4];
    int t = threadIdx.x, lane = t & 63, wv = t >> 6;
    int wm = wv & 1, wn = wv >> 1;          // 2 M-waves x 4 N-waves
    int m0 = blockIdx.x * 64;
    int b = m0 >> 12;
    // --- precompute bilinear corners for 64 tokens x 9 points ---
    for (int i = t; i < 576; i += 512) {
        int mi = i / 9, p = i % 9;
        int m = m0 + mi;
        int hw = m & 4095;
        int h = hw >> 6, w = hw & 63;
        float ox = off[(size_t)m * 18 + p];
        float oy = off[(size_t)m * 18 + 9 + p];
        float px = ox + (float)(h + 1) + (float)(p / 3 - 1);
        float py = oy + (float)(w + 1) + (float)(p % 3 - 1);
        float fx = floorf(px), fy = floorf(py);
        float qlx = fminf(fmaxf(fx, 0.f), 65.f);
        float qly = fminf(fmaxf(fy, 0.f), 65.f);
        float qrx = fminf(fmaxf(fx + 1.f, 0.f), 65.f);
        float qry = fminf(fmaxf(fy + 1.f, 0.f), 65.f);
        float pxc = fminf(fmaxf(px, 0.f), 65.f);
        float pyc = fminf(fmaxf(py, 0.f), 65.f);
        float gxl = 1.f + (qlx - pxc), gxr = 1.f - (qrx - pxc);
        float gyl = 1.f + (qly - pyc), gyr = 1.f - (qry - pyc);
        int xl = (int)qlx, xr = (int)qrx, yl = (int)qly, yr = (int)qry;
        int cx[4] = {xl, xr, xl, xr};
        int cy[4] = {yl, yr, yr, yl};
        float cw[4] = {gxl * gyl, gxr * gyr, gxl * gyr, gxr * gyl};
#pragma unroll
        for (int k = 0; k < 4; k++) {
            bool ok = (cx[k] >= 1) && (cx[k] <= 64) && (cy[k] >= 1) && (cy[k] <= 64);
            sidx[mi][p][k] = ok ? (b * 4096 + (cx[k] - 1) * 64 + (cy[k] - 1)) * 192 : 0;
            swt[mi][p][k] = ok ? cw[k] : 0.f;
        }
    }
    __syncthreads();
    f32x4 acc[2][3];
#pragma unroll
    for (int i = 0; i < 2; i++)
#pragma unroll
        for (int j = 0; j < 3; j++) {
            acc[i][j][0] = 0.f; acc[i][j][1] = 0.f; acc[i][j][2] = 0.f; acc[i][j][3] = 0.f;
        }
    // gather: thread owns token mi = t>>3, 24-channel strip ch
    int mi = t >> 3, ch = (t & 7) * 24;
    // B-frag row constants (per wave)
    int orow[3], oxr[3];
#pragma unroll
    for (int j = 0; j < 3; j++) {
        int o = wn * 48 + j * 16 + (lane & 15);
        orow[j] = o * 192;
        oxr[j] = (o & 7) << 3;
    }
    int kb0 = (lane >> 4) * 8;

    // --- prologue: stage B tap0, gather tap0 -> As ---
    {
        const u16* bsrc = wdT;              // tap 0 slice
#pragma unroll
        for (int i2 = 0; i2 < 9; i2++) {
            int jc = wv + 8 * i2;
            gll16(bsrc + jc * 512 + lane * 8, Bs + jc * 512);
        }
        const int*   si = sidx[mi][0];
        const float* sw = swt[mi][0];
        s16x8 pc[4][3];
#pragma unroll
        for (int k = 0; k < 4; k++)
#pragma unroll
            for (int s = 0; s < 3; s++)
                pc[k][s] = *(const s16x8*)(xn + si[k] + ch + s * 8);
        float v[24];
#pragma unroll
        for (int j = 0; j < 24; j++) v[j] = 0.f;
#pragma unroll
        for (int k = 0; k < 4; k++) {
            float wt = sw[k];
#pragma unroll
            for (int j = 0; j < 24; j++) v[j] += wt * bf2f((u16)pc[k][j >> 3][j & 7]);
        }
#pragma unroll
        for (int s = 0; s < 3; s++) {
            s16x8 ov;
#pragma unroll
            for (int e = 0; e < 8; e++) ov[e] = (short)f2bf(v[s * 8 + e]);
            *(s16x8*)&As[mi * 200 + ch + s * 8] = ov;
        }
        asm volatile("s_waitcnt vmcnt(0)" ::: "memory");
        __syncthreads();
    }

    for (int p = 0; p < 9; p++) {
        // --- issue next-tap corner loads early (hide under MFMA) ---
        s16x8 nc[4][3];
        if (p < 8) {
            const int* si = sidx[mi][p + 1];
#pragma unroll
            for (int k = 0; k < 4; k++)
#pragma unroll
                for (int s = 0; s < 3; s++)
                    nc[k][s] = *(const s16x8*)(xn + si[k] + ch + s * 8);
        }
        // --- MFMA: 6 k-steps from LDS (A stride-200, B XOR-swizzled) ---
#pragma unroll
        for (int kk = 0; kk < 6; kk++) {
            int kb = kk * 32 + kb0;
            s16x8 af[2], bfr[3];
#pragma unroll
            for (int i = 0; i < 2; i++)
                af[i] = *(const s16x8*)&As[(wm * 32 + i * 16 + (lane & 15)) * 200 + kb];
#pragma unroll
            for (int j = 0; j < 3; j++)
                bfr[j] = *(const s16x8*)&Bs[orow[j] + (kb ^ oxr[j])];
#pragma unroll
            for (int i = 0; i < 2; i++)
#pragma unroll
                for (int j = 0; j < 3; j++)
                    acc[i][j] = __builtin_amdgcn_mfma_f32_16x16x32_bf16(af[i], bfr[j], acc[i][j], 0, 0, 0);
        }
        if (p < 8) {
            __syncthreads();                // all waves done reading As/Bs
            // --- stage B tap p+1 (coalesced, latency hides under weighting) ---
            const u16* bsrc = wdT + (size_t)(p + 1) * 36864;
#pragma unroll
            for (int i2 = 0; i2 < 9; i2++) {
                int jc = wv + 8 * i2;
                gll16(bsrc + jc * 512 + lane * 8, Bs + jc * 512);
            }
            // --- weight corners -> As ---
            const float* sw = swt[mi][p + 1];
            float v[24];
#pragma unroll
            for (int j = 0; j < 24; j++) v[j] = 0.f;
#pragma unroll
            for (int k = 0; k < 4; k++) {
                float wt = sw[k];
#pragma unroll
                for (int j = 0; j < 24; j++) v[j] += wt * bf2f((u16)nc[k][j >> 3][j & 7]);
            }
#pragma unroll
            for (int s = 0; s < 3; s++) {
                s16x8 ov;
#pragma unroll
                for (int e = 0; e < 8; e++) ov[e] = (short)f2bf(v[s * 8 + e]);
                *(s16x8*)&As[mi * 200 + ch + s * 8] = ov;
            }
            asm volatile("s_waitcnt vmcnt(0)" ::: "memory");
            __syncthreads();                // staged B + As visible
        }
    }
    int col = lane & 15;
#pragma unroll
    for (int i = 0; i < 2; i++)
#pragma unroll
        for (int j = 0; j < 3; j++) {
            int mm = m0 + wm * 32 + i * 16 + (lane >> 4) * 4;
            int nn = wn * 48 + j * 16 + col;
#pragma unroll
            for (int r = 0; r < 4; r++)
                qt[(size_t)(mm + r) * 192 + nn] = f2bf(acc[i][j][r]);
        }
}

// ---------------------------------------------------------------------------
// templated bf16 MFMA GEMM: C[M,N] = A[M,K] * B^T[N,K].
// 2-PHASE DOUBLE-BUFFERED staging (T3-minimum): stage(t+1) issued BEFORE
// computing tile t; single vmcnt(0)+barrier per k-step at the END, so the
// global->LDS latency of t+1 overlaps ds_read+MFMA of t.
// EP: 2 = +bias,gelu -> bf16
//     4 = +x residual (NCHW) -> xs2 fp32 AND fused LN2 -> h1 bf16 (needs BN==ldc)
//     5 = +bias + xs2 -> out fp32 NCHW transposed (fused final)
//     6 = bf16 store + fused l2norm col sums (atomicAdd to out2)
// ---------------------------------------------------------------------------
template<int BM, int BN, int WM, int WN, int EP>
__global__ __launch_bounds__((BM / WM) * (BN / WN) * 64)
void gemm_bt(const u16* __restrict__ A, int lda,
             const u16* __restrict__ B, int ldb, int bstride,
             void* __restrict__ out, int ldc,
             const float* __restrict__ ex1, int K,
             const float* __restrict__ ex2,
             const float* __restrict__ exg, const float* __restrict__ exb,
             void* __restrict__ out2)
{
    constexpr int BK = 32;
    constexpr int WAVES_M = BM / WM, WAVES_N = BN / WN, NW = WAVES_M * WAVES_N;
    constexpr int TM = WM / 16, TN = WN / 16;
    constexpr int NLA = BM / 16, NLB = BN / 16;   // 1KB global_load_lds chunks
    __shared__ u16 As[2][BM * BK];
    __shared__ u16 Bs[2][BN * BK];
    int tid = threadIdx.x;
    int lane = tid & 63, wv = tid >> 6;
    int wm = wv % WAVES_M, wn = wv / WAVES_M;
    int m0 = blockIdx.x * BM, n0 = blockIdx.y * BN;
    const u16* Bp = B + (size_t)(m0 >> 12) * bstride;
    f32x4 acc[TM][TN];
#pragma unroll
    for (int i = 0; i < TM; i++)
#pragma unroll
        for (int j = 0; j < TN; j++) {
            acc[i][j][0] = 0.f; acc[i][j][1] = 0.f; acc[i][j][2] = 0.f; acc[i][j][3] = 0.f;
        }
    int arow_l = lane >> 2;
    int acol_l = (lane & 3) * 8;

    // --- prologue: stage tile 0 into buffer 0 ---
#pragma unroll 1
    for (int j = wv; j < NLA + NLB; j += NW) {
        if (j < NLA) {
            int row = j * 16 + arow_l;
            gll16(A + (size_t)(m0 + row) * lda + acol_l, As[0] + j * 512);
        } else {
            int row = (j - NLA) * 16 + arow_l;
            gll16(Bp + (size_t)(n0 + row) * ldb + acol_l, Bs[0] + (j - NLA) * 512);
        }
    }
    asm volatile("s_waitcnt vmcnt(0)" ::: "memory");
    __syncthreads();

    int buf = 0;
    for (int k0 = 0; k0 < K; k0 += BK) {
        // --- issue next-tile staging into buf^1 (latency hides under MFMA) ---
        if (k0 + BK < K) {
            int kn = k0 + BK;
#pragma unroll 1
            for (int j = wv; j < NLA + NLB; j += NW) {
                if (j < NLA) {
                    int row = j * 16 + arow_l;
                    gll16(A + (size_t)(m0 + row) * lda + kn + acol_l, As[buf ^ 1] + j * 512);
                } else {
                    int row = (j - NLA) * 16 + arow_l;
                    gll16(Bp + (size_t)(n0 + row) * ldb + kn + acol_l, Bs[buf ^ 1] + (j - NLA) * 512);
                }
            }
        }
        // --- compute current tile from LDS ---
        s16x8 af[TM], bfr[TN];
#pragma unroll
        for (int i = 0; i < TM; i++)
            af[i] = *(const s16x8*)&As[buf][(wm * WM + i * 16 + (lane & 15)) * BK + (lane >> 4) * 8];
#pragma unroll
        for (int j = 0; j < TN; j++)
            bfr[j] = *(const s16x8*)&Bs[buf][(wn * WN + j * 16 + (lane & 15)) * BK + (lane >> 4) * 8];
#pragma unroll
        for (int i = 0; i < TM; i++)
#pragma unroll
            for (int j = 0; j < TN; j++)
                acc[i][j] = __builtin_amdgcn_mfma_f32_16x16x32_bf16(af[i], bfr[j], acc[i][j], 0, 0, 0);
        // --- wait next-tile loads + all reads of buf, then swap ---
        asm volatile("s_waitcnt vmcnt(0)" ::: "memory");
        __syncthreads();
        buf ^= 1;
    }
    // epilogue: C row = (lane>>4)*4 + r, col = lane&15
    int col = lane & 15;
    int rg = lane >> 4;
    if constexpr (EP == 2) {
        u16* o = (u16*)out;
#pragma unroll
        for (int i = 0; i < TM; i++)
#pragma unroll
            for (int j = 0; j < TN; j++) {
                int mm = m0 + wm * WM + i * 16 + rg * 4;
                int nn = n0 + wn * WN + j * 16 + col;
                float bb = ex1[nn];
#pragma unroll
                for (int r = 0; r < 4; r++) {
                    float v = acc[i][j][r] + bb;
                    o[(size_t)(mm + r) * ldc + nn] = f2bf(0.5f * v * (1.f + erff(v * 0.70710678118654752f)));
                }
            }
    } else if constexpr (EP == 4) {
        // v = acc + x residual; full-row LN (BN == ldc); write xs2 fp32 + h1 bf16
        __shared__ float lnA[BM][WAVES_N];  // row sums per wn-slice
        __shared__ float lnB[BM][WAVES_N];  // row sumsq per wn-slice
        float v[TM][TN][4];
        float sr[TM][4], sq[TM][4];
#pragma unroll
        for (int i = 0; i < TM; i++)
#pragma unroll
            for (int r = 0; r < 4; r++) { sr[i][r] = 0.f; sq[i][r] = 0.f; }
#pragma unroll
        for (int i = 0; i < TM; i++) {
            int mm = m0 + wm * WM + i * 16 + rg * 4;
#pragma unroll
            for (int j = 0; j < TN; j++) {
                int nn = n0 + wn * WN + j * 16 + col;
                const float* xr = ex1 + (size_t)(mm >> 12) * 786432 + (size_t)nn * 4096 + (mm & 4095);
#pragma unroll
                for (int r = 0; r < 4; r++) {
                    float vv = acc[i][j][r] + xr[r];
                    v[i][j][r] = vv;
                    sr[i][r] += vv; sq[i][r] += vv * vv;
                }
            }
        }
#pragma unroll
        for (int i = 0; i < TM; i++)
#pragma unroll
            for (int r = 0; r < 4; r++)
#pragma unroll
                for (int sh = 1; sh < 16; sh <<= 1) {
                    sr[i][r] += __shfl_xor(sr[i][r], sh);
                    sq[i][r] += __shfl_xor(sq[i][r], sh);
                }
        if (col == 0) {
#pragma unroll
            for (int i = 0; i < TM; i++)
#pragma unroll
                for (int r = 0; r < 4; r++) {
                    int row = wm * WM + i * 16 + rg * 4 + r;
                    lnA[row][wn] = sr[i][r];
                    lnB[row][wn] = sq[i][r];
                }
        }
        __syncthreads();
        float* oxs = (float*)out;
        u16* oh = (u16*)out2;
#pragma unroll
        for (int i = 0; i < TM; i++) {
            int mm = m0 + wm * WM + i * 16 + rg * 4;
#pragma unroll
            for (int r = 0; r < 4; r++) {
                int row = wm * WM + i * 16 + rg * 4 + r;
                float tot = 0.f, tq = 0.f;
#pragma unroll
                for (int q2 = 0; q2 < WAVES_N; q2++) { tot += lnA[row][q2]; tq += lnB[row][q2]; }
                float mu = tot * (1.f / 192.f);
                float var = tq * (1.f / 192.f) - mu * mu;
                float rstd = rsqrtf(var + 1e-5f);
#pragma unroll
                for (int j = 0; j < TN; j++) {
                    int nn = n0 + wn * WN + j * 16 + col;
                    float vv = v[i][j][r];
                    oxs[(size_t)(mm + r) * ldc + nn] = vv;
                    oh[(size_t)(mm + r) * ldc + nn] = f2bf((vv - mu) * rstd * exg[nn] + exb[nn]);
                }
            }
        }
    } else if constexpr (EP == 5) {
        // out = acc + bias + xs2, written NCHW transposed (fused final)
        float* o = (float*)out;
#pragma unroll
        for (int i = 0; i < TM; i++)
#pragma unroll
            for (int j = 0; j < TN; j++) {
                int mm = m0 + wm * WM + i * 16 + rg * 4;
                int nn = n0 + wn * WN + j * 16 + col;
                float bb = ex1[nn];
                size_t obase = (size_t)(mm >> 12) * 786432 + (size_t)nn * 4096;
#pragma unroll
                for (int r = 0; r < 4; r++) {
                    float vv = acc[i][j][r] + bb + ex2[(size_t)(mm + r) * ldc + nn];
                    o[obase + ((mm + r) & 4095)] = vv;
                }
            }
    } else if constexpr (EP == 6) {
        // bf16 store + fused l2norm column sums (on rounded values = old math)
        u16* o = (u16*)out;
        float* nrm = (float*)out2;
        int bI = m0 >> 12;
#pragma unroll
        for (int j = 0; j < TN; j++) {
            float s = 0.f;
#pragma unroll
            for (int i = 0; i < TM; i++) {
                int mm = m0 + wm * WM + i * 16 + rg * 4;
                int nn = n0 + wn * WN + j * 16 + col;
#pragma unroll
                for (int r = 0; r < 4; r++) {
                    u16 hb = f2bf(acc[i][j][r]);
                    o[(size_t)(mm + r) * ldc + nn] = hb;
                    float fv = bf2f(hb);
                    s += fv * fv;
                }
            }
            s += __shfl_xor(s, 16);
            s += __shfl_xor(s, 32);
            if (rg == 0) {
                int nn = n0 + wn * WN + j * 16 + col;
                atomicAdd(&nrm[bI * 384 + nn], s);
            }
        }
    }
}

// ---------------------------------------------------------------------------
// attention logits partials: raw[bh][ch][c][d] = sum_{r in chunk} q[r][c]*k[r][d]
// non-atomic private slabs; global loads vectorized (s16x8).
// ---------------------------------------------------------------------------
__global__ __launch_bounds__(64) void attnp_kernel(const u16* __restrict__ qt,
                                                   const u16* __restrict__ kvt,
                                                   float* __restrict__ raw)
{
    __shared__ float qT[32 * 69];
    __shared__ float kT[32 * 69];
    int ch = blockIdx.x, h = blockIdx.y, b = blockIdx.z;
    int t = threadIdx.x;
    size_t base = (size_t)(b * 4096 + ch * 64);
#pragma unroll
    for (int i = 0; i < 4; i++) {
        int e = t + i * 64;                 // 0..255: 64 rows x 4 8-ch chunks
        int r = e >> 2, c8 = (e & 3) * 8;
        s16x8 qv = *(const s16x8*)(qt + (base + r) * 192 + h * 32 + c8);
        s16x8 kv = *(const s16x8*)(kvt + (base + r) * 384 + h * 32 + c8);
#pragma unroll
        for (int j = 0; j < 8; j++) {
            qT[(c8 + j) * 69 + r] = bf2f((u16)qv[j]);
            kT[(c8 + j) * 69 + r] = bf2f((u16)kv[j]);
        }
    }
    __syncthreads();
    int tc = t >> 3, td = t & 7;
    int c0 = tc * 4, d0 = td * 4;
    float acc[4][4] = {};
    for (int r = 0; r < 64; r++) {
        float qv[4], kv4[4];
#pragma unroll
        for (int u = 0; u < 4; u++) { qv[u] = qT[(c0 + u) * 69 + r]; kv4[u] = kT[(d0 + u) * 69 + r]; }
#pragma unroll
        for (int u = 0; u < 4; u++)
#pragma unroll
            for (int v = 0; v < 4; v++) acc[u][v] += qv[u] * kv4[v];
    }
    float* dst = raw + (((size_t)(b * 6 + h) * 64 + ch) * 1024);
#pragma unroll
    for (int u = 0; u < 4; u++)
#pragma unroll
        for (int v = 0; v < 4; v++)
            dst[(c0 + u) * 32 + d0 + v] = acc[u][v];
}

// ---------------------------------------------------------------------------
// fused softmax + mb: sums the 64 attnp partials, k-norm + temperature folded,
// softmax over d, v-norm folded; att2 kept in LDS; then
// Mb[b][o2][h*32+d] = sum_c w_proj[o2][h*32+c] * att2[c][d] (same fp32 order
// as the old mb_kernel). One block per (b,h).
// ---------------------------------------------------------------------------
__global__ __launch_bounds__(1024) void attnfin_kernel(const float* __restrict__ raw,
                                                       const float* __restrict__ norm2,
                                                       const float* __restrict__ temp,
                                                       const float* __restrict__ wproj,
                                                       u16* __restrict__ Mb)
{
    int h = blockIdx.x, b = blockIdx.y;
    int t = threadIdx.x;
    int c = t >> 5, d = t & 31;
    __shared__ float invk[32], invv[32];
    __shared__ float attL[32][33];
    if (t < 32)       invk[t] = 1.f / fmaxf(sqrtf(norm2[b * 384 + h * 32 + t]), 1e-12f);
    else if (t < 64)  invv[t - 32] = 1.f / fmaxf(sqrtf(norm2[b * 384 + 192 + h * 32 + (t - 32)]), 1e-12f);
    __syncthreads();
    float T = temp[h];
    const float* pr = raw + (size_t)(b * 6 + h) * 65536 + c * 32 + d;
    float v = 0.f;
#pragma unroll
    for (int ch = 0; ch < 64; ch++) v += pr[ch * 1024];
    v *= invk[d] * T;
    float mx = v;
    for (int s = 16; s > 0; s >>= 1) mx = fmaxf(mx, __shfl_xor(mx, s, 32));
    float e = expf(v - mx);
    float sm = e;
    for (int s = 16; s > 0; s >>= 1) sm += __shfl_xor(sm, s, 32);
    attL[c][d] = (e / sm) * invv[d];
    __syncthreads();
    // mb phase: 192 x 32 outputs, 6 per thread
#pragma unroll
    for (int i2 = 0; i2 < 6; i2++) {
        int i = t + i2 * 1024;
        int o2 = i >> 5, dd = i & 31;
        float s = 0.f;
#pragma unroll
        for (int c2 = 0; c2 < 32; c2++)
            s += wproj[o2 * 192 + h * 32 + c2] * attL[c2][dd];
        Mb[((size_t)b * 192 + o2) * 192 + h * 32 + dd] = f2bf(s);
    }
}

// ---------------------------------------------------------------------------
extern "C" void kernel_launch(void* const* d_in, const int* in_sizes, int n_in,
                              void* d_out, int out_size, void* d_ws, size_t ws_size,
                              hipStream_t stream)
{
    const float* x      = (const float*)d_in[0];
    const float* gamma1 = (const float*)d_in[1];
    const float* beta1  = (const float*)d_in[2];
    const float* gamma2 = (const float*)d_in[3];
    const float* beta2  = (const float*)d_in[4];
    const float* temp   = (const float*)d_in[5];
    const float* w_qkv  = (const float*)d_in[6];
    const float* w_proj = (const float*)d_in[7];
    const float* w_p    = (const float*)d_in[8];
    const float* b_p    = (const float*)d_in[9];
    const float* w_d    = (const float*)d_in[10];
    const float* w_fc1  = (const float*)d_in[11];
    const float* b_fc1  = (const float*)d_in[12];
    const float* w_fc2  = (const float*)d_in[13];
    const float* b_fc2  = (const float*)d_in[14];
    float* out = (float*)d_out;
    char* ws = (char*)d_ws;

    u16*   xn    = (u16*)(ws + 0);                     // 6.29 MB (aliased: h1)
    float* off   = (float*)(ws + 6291456);             // 1.18 MB
    u16*   adef  = (u16*)(ws + 7471104);               // region (aliased: m1, wpT)
    u16*   wpT   = adef;                               // 110 KB, dead once offconv runs
    u16*   m1    = adef;                               // 25.2 MB
    float* araw  = (float*)(ws + 32636928);            // 6.29 MB attnp partials
    u16*   qt    = (u16*)(ws + 64094208);              // 6.29 MB
    u16*   kvt   = (u16*)(ws + 70385664);              // 12.6 MB
    float* norm2 = (float*)(ws + 82968576);            // 6 KB
    u16*   Mb    = (u16*)(ws + 83171328);              // 144 KB
    float* xs2   = (float*)(ws + 83318784);            // 12.6 MB
    u16*   h1    = xn;
    u16*   wdT   = (u16*)(ws + 95901696);
    u16*   wkvT  = (u16*)(ws + 96565248);
    u16*   wf1T  = (u16*)(ws + 96712704);
    u16*   wf2T  = (u16*)(ws + 97007616);              // end 97302528 B

    prep_kernel<<<1296, 256, 0, stream>>>(w_d, w_qkv, w_fc1, w_fc2, w_p, wdT, wkvT, wf1T, wf2T, wpT, norm2);
    ln1_kernel<<<256, 256, 0, stream>>>(x, gamma1, beta1, xn);
    offconv_kernel<<<256, 512, 0, stream>>>(xn, wpT, b_p, off);
    // fused gather + deform output conv: M=16384 K=1728 N=192, BM=64, 8 waves
    gemm_deform<<<256, 512, 0, stream>>>(xn, off, wdT, qt);
    // k,v projection + fused l2norm sums: M=16384 K=192 N=384
    gemm_bt<128, 128, 64, 64, 6><<<dim3(128, 3), 256, 0, stream>>>(
        xn, 192, wkvT, 192, 0, kvt, 384, nullptr, 192, nullptr, nullptr, nullptr, norm2);
    attnp_kernel<<<dim3(64, 6, 4), 64, 0, stream>>>(qt, kvt, araw);
    // fused softmax + mb (att2 in LDS)
    attnfin_kernel<<<dim3(6, 4), 1024, 0, stream>>>(araw, norm2, temp, w_proj, Mb);
    // attn-apply + proj GEMM + x residual -> xs2 fp32, fused LN2 -> h1 bf16
    gemm_bt<64, 192, 32, 48, 4><<<dim3(256, 1), 512, 0, stream>>>(
        kvt + 192, 384, Mb, 192, 192 * 192, xs2, 192, x, 192, nullptr, gamma2, beta2, h1);
    // fc1 + gelu: M=16384 K=192 N=768
    gemm_bt<128, 128, 64, 64, 2><<<dim3(128, 6), 256, 0, stream>>>(
        h1, 192, wf1T, 192, 0, m1, 768, b_fc1, 192, nullptr, nullptr, nullptr, nullptr);
    // fc2 + bias + xs2, fused final transpose -> out NCHW fp32 (8 waves, 4M x 2N)
    gemm_bt<128, 96, 32, 48, 5><<<dim3(128, 2), 512, 0, stream>>>(
        m1, 768, wf2T, 768, 0, out, 192, b_fc2, 768, xs2, nullptr, nullptr, nullptr);
}

// Round 10
// 243.308 us; speedup vs baseline: 1.0194x; 1.0194x over previous
//
#include <hip/hip_runtime.h>
#include <math.h>

typedef unsigned short u16;
typedef unsigned int u32;
typedef short s16x8 __attribute__((ext_vector_type(8)));
typedef float f32x4 __attribute__((ext_vector_type(4)));

#define AS1 __attribute__((address_space(1)))
#define AS3 __attribute__((address_space(3)))

__device__ __forceinline__ float bf2f(u16 u) {
    union { u32 i; float f; } v; v.i = ((u32)u) << 16; return v.f;
}
__device__ __forceinline__ u16 f2bf(float f) {
    union { float f; u32 i; } v; v.f = f;
    u32 r = v.i + 0x7fffu + ((v.i >> 16) & 1u);
    return (u16)(r >> 16);
}
__device__ __forceinline__ void gll16(const u16* g, u16* l) {
    __builtin_amdgcn_global_load_lds((const AS1 u32*)g, (AS3 u32*)l, 16, 0, 0);
}

// ---------------------------------------------------------------------------
// prep: repack weights to B^T bf16 layouts for the MFMA GEMMs; zero norm2
// (folds the old hipMemsetAsync dispatch). wdT is TAP-MAJOR + XOR-swizzled:
//   wdT[(p*192 + o)*192 + (c ^ ((o&7)<<3))] = w_d[o][c][p]
// ---------------------------------------------------------------------------
__global__ void prep_kernel(const float* __restrict__ wd, const float* __restrict__ wqkv,
                            const float* __restrict__ wfc1, const float* __restrict__ wfc2,
                            const float* __restrict__ wp,
                            u16* __restrict__ wdT, u16* __restrict__ wkvT,
                            u16* __restrict__ wf1T, u16* __restrict__ wf2T,
                            u16* __restrict__ wpT, float* __restrict__ norm2)
{
    int i = blockIdx.x * 256 + threadIdx.x;
    if (i < 1536) norm2[i] = 0.f;           // 4 batches x 384 cols
    if (i < 331776) {                       // tap-major swizzled w_d
        int o = i / 1728, r = i % 1728;
        int p = r / 192, c = r % 192;
        int cs = c ^ ((o & 7) << 3);
        wdT[(p * 192 + o) * 192 + cs] = f2bf(wd[(o * 192 + c) * 9 + p]);
    }
    if (i < 73728) {                        // rows C..3C of w_qkv (k,v only)
        int o = i / 192, c = i % 192;
        wkvT[i] = f2bf(wqkv[(192 + o) * 192 + c]);
    }
    if (i < 147456) {
        int n = i / 192, c = i % 192;       // w_fc1 (192,768) -> [768][192]
        wf1T[i] = f2bf(wfc1[c * 768 + n]);
        int n2 = i / 768, hh = i % 768;     // w_fc2 (768,192) -> [192][768]
        wf2T[i] = f2bf(wfc2[hh * 192 + n2]);
    }
    if (i < 31104) {                        // w_pT[n][p*192+c] = w_p[n][c][p], pad to 32 rows
        int n = i / 1728, r = i % 1728;
        int p = r / 192, c = r % 192;
        wpT[i] = f2bf(wp[(n * 192 + c) * 9 + p]);
    } else if (i < 55296) {
        wpT[i] = 0;
    }
}

// ---------------------------------------------------------------------------
// LN1: x NCHW fp32 -> xn token-major bf16 [16384][192]; x read once (LDS stage)
// ---------------------------------------------------------------------------
__global__ __launch_bounds__(256) void ln1_kernel(const float* __restrict__ x,
                                                  const float* __restrict__ g,
                                                  const float* __restrict__ be,
                                                  u16* __restrict__ xn)
{
    __shared__ float red0[256], red1[256];
    __shared__ float mu_s[64], rs_s[64];
    __shared__ float xt[64 * 193];          // fp32 stage, stride 193 = conflict-free
    __shared__ u16 tile[64 * 194];          // bf16 out, stride 194 (97 dwords)
    int t = threadIdx.x, tl = t & 63, cg = t >> 6;
    int m0 = blockIdx.x * 64;
    int b = m0 >> 12, hw0 = m0 & 4095;
    const float* xb = x + (size_t)b * 786432 + hw0 + tl;
    float s = 0.f, s2 = 0.f;
    for (int cc = cg; cc < 192; cc += 4) {
        float v = xb[cc * 4096];
        xt[tl * 193 + cc] = v;
        s += v; s2 += v * v;
    }
    red0[t] = s; red1[t] = s2;
    __syncthreads();
    if (t < 64) {
        float a = red0[t] + red0[64 + t] + red0[128 + t] + red0[192 + t];
        float q = red1[t] + red1[64 + t] + red1[128 + t] + red1[192 + t];
        float mu = a * (1.f / 192.f);
        float var = q * (1.f / 192.f) - mu * mu;
        mu_s[t] = mu; rs_s[t] = rsqrtf(var + 1e-5f);
    }
    __syncthreads();
    float mu = mu_s[tl], rs = rs_s[tl];
    for (int cc = cg; cc < 192; cc += 4) {
        float v = (xt[tl * 193 + cc] - mu) * rs * g[cc] + be[cc];
        tile[tl * 194 + cc] = f2bf(v);
    }
    __syncthreads();
    u32* dst = (u32*)(xn + (size_t)m0 * 192);
    for (int i = t; i < 64 * 96; i += 256) {
        int r = i / 96, c2 = i % 96;
        dst[i] = *(const u32*)&tile[r * 194 + c2 * 2];
    }
}

// ---------------------------------------------------------------------------
// offset conv as direct MFMA conv: one block per (b,h) row, BM=64 (w axis),
// N=32 (18 padded), K = 9 taps x 192 ch.
// 8 waves (512 thr), wave grid 4M x 2N -> 2 waves/SIMD.
// ---------------------------------------------------------------------------
__global__ __launch_bounds__(512) void offconv_kernel(const u16* __restrict__ xn,
                                                      const u16* __restrict__ wpT,
                                                      const float* __restrict__ bp,
                                                      float* __restrict__ off)
{
    __shared__ u16 As[64 * 200];            // stride 200: rows rotate 4 banks
    __shared__ u16 Bs[32 * 200];
    int bh = blockIdx.x;
    int b = bh >> 6, h = bh & 63;
    int t = threadIdx.x;
    int lane = t & 63, wv = t >> 6;
    int wm = wv & 3, wn = wv >> 2;          // 4 M-waves x 2 N-waves
    f32x4 acc;
    acc[0] = 0.f; acc[1] = 0.f; acc[2] = 0.f; acc[3] = 0.f;
    int r = t >> 3, cq = (t & 7) * 24;      // 8 threads per A row, 24 ch each
    for (int p = 0; p < 9; p++) {
        int dh = p / 3 - 1, dw = p % 3 - 1;
        int hr = h + dh, wr = r + dw;
        bool valid = (hr >= 0) && (hr < 64) && (wr >= 0) && (wr < 64);
        const u16* src = xn + ((size_t)(b * 4096 + hr * 64 + wr)) * 192 + cq;
#pragma unroll
        for (int j = 0; j < 3; j++) {
            s16x8 v = {0, 0, 0, 0, 0, 0, 0, 0};
            if (valid) v = *(const s16x8*)(src + j * 8);
            *(s16x8*)&As[r * 200 + cq + j * 8] = v;
        }
#pragma unroll
        for (int i = 0; i < 2; i++) {
            int q = t + i * 512;
            if (q < 768) {
                int n = q / 24, c8 = q % 24;
                *(s16x8*)&Bs[n * 200 + c8 * 8] =
                    *(const s16x8*)(wpT + n * 1728 + p * 192 + c8 * 8);
            }
        }
        __syncthreads();
#pragma unroll
        for (int kc = 0; kc < 6; kc++) {
            s16x8 af = *(const s16x8*)&As[(wm * 16 + (lane & 15)) * 200 + kc * 32 + (lane >> 4) * 8];
            s16x8 b0 = *(const s16x8*)&Bs[(wn * 16 + (lane & 15)) * 200 + kc * 32 + (lane >> 4) * 8];
            acc = __builtin_amdgcn_mfma_f32_16x16x32_bf16(af, b0, acc, 0, 0, 0);
        }
        __syncthreads();
    }
    int col = lane & 15;
    int n = wn * 16 + col;
    int wbase = wm * 16 + (lane >> 4) * 4;
    if (n < 18) {
        float bb = bp[n];
#pragma unroll
        for (int rr = 0; rr < 4; rr++) {
            int w = wbase + rr;
            off[((size_t)(b * 4096 + h * 64 + w)) * 18 + n] = acc[rr] + bb;
        }
    }
}

// ---------------------------------------------------------------------------
// fused bilinear-gather + deform output conv GEMM. BM=64, 8 waves, B staged
// once per tap into LDS from tap-major pre-swizzled wdT. (R3 structure.)
// ---------------------------------------------------------------------------
__global__ __launch_bounds__(512, 2) void gemm_deform(const u16* __restrict__ xn,
                                                      const float* __restrict__ off,
                                                      const u16* __restrict__ wdT,
                                                      u16* __restrict__ qt)
{
    __shared__ u16 As[64 * 200];            // [token][ch], stride 200 rotates banks
    __shared__ u16 Bs[192 * 192];           // per-tap B panel, XOR-swizzled cols
    __shared__ int sidx[64][9][4];
    __shared__ float swt[64][9][4];
    int t = threadIdx.x, lane = t & 63, wv = t >> 6;
    int wm = wv & 1, wn = wv >> 1;          // 2 M-waves x 4 N-waves
    int m0 = blockIdx.x * 64;
    int b = m0 >> 12;
    // --- precompute bilinear corners for 64 tokens x 9 points ---
    for (int i = t; i < 576; i += 512) {
        int mi = i / 9, p = i % 9;
        int m = m0 + mi;
        int hw = m & 4095;
        int h = hw >> 6, w = hw & 63;
        float ox = off[(size_t)m * 18 + p];
        float oy = off[(size_t)m * 18 + 9 + p];
        float px = ox + (float)(h + 1) + (float)(p / 3 - 1);
        float py = oy + (float)(w + 1) + (float)(p % 3 - 1);
        float fx = floorf(px), fy = floorf(py);
        float qlx = fminf(fmaxf(fx, 0.f), 65.f);
        float qly = fminf(fmaxf(fy, 0.f), 65.f);
        float qrx = fminf(fmaxf(fx + 1.f, 0.f), 65.f);
        float qry = fminf(fmaxf(fy + 1.f, 0.f), 65.f);
        float pxc = fminf(fmaxf(px, 0.f), 65.f);
        float pyc = fminf(fmaxf(py, 0.f), 65.f);
        float gxl = 1.f + (qlx - pxc), gxr = 1.f - (qrx - pxc);
        float gyl = 1.f + (qly - pyc), gyr = 1.f - (qry - pyc);
        int xl = (int)qlx, xr = (int)qrx, yl = (int)qly, yr = (int)qry;
        int cx[4] = {xl, xr, xl, xr};
        int cy[4] = {yl, yr, yr, yl};
        float cw[4] = {gxl * gyl, gxr * gyr, gxl * gyr, gxr * gyl};
#pragma unroll
        for (int k = 0; k < 4; k++) {
            bool ok = (cx[k] >= 1) && (cx[k] <= 64) && (cy[k] >= 1) && (cy[k] <= 64);
            sidx[mi][p][k] = ok ? (b * 4096 + (cx[k] - 1) * 64 + (cy[k] - 1)) * 192 : 0;
            swt[mi][p][k] = ok ? cw[k] : 0.f;
        }
    }
    __syncthreads();
    f32x4 acc[2][3];
#pragma unroll
    for (int i = 0; i < 2; i++)
#pragma unroll
        for (int j = 0; j < 3; j++) {
            acc[i][j][0] = 0.f; acc[i][j][1] = 0.f; acc[i][j][2] = 0.f; acc[i][j][3] = 0.f;
        }
    // gather: thread owns token mi = t>>3, 24-channel strip ch
    int mi = t >> 3, ch = (t & 7) * 24;
    // B-frag row constants (per wave)
    int orow[3], oxr[3];
#pragma unroll
    for (int j = 0; j < 3; j++) {
        int o = wn * 48 + j * 16 + (lane & 15);
        orow[j] = o * 192;
        oxr[j] = (o & 7) << 3;
    }
    int kb0 = (lane >> 4) * 8;

    // --- prologue: stage B tap0, gather tap0 -> As ---
    {
        const u16* bsrc = wdT;              // tap 0 slice
#pragma unroll
        for (int i2 = 0; i2 < 9; i2++) {
            int jc = wv + 8 * i2;
            gll16(bsrc + jc * 512 + lane * 8, Bs + jc * 512);
        }
        const int*   si = sidx[mi][0];
        const float* sw = swt[mi][0];
        s16x8 pc[4][3];
#pragma unroll
        for (int k = 0; k < 4; k++)
#pragma unroll
            for (int s = 0; s < 3; s++)
                pc[k][s] = *(const s16x8*)(xn + si[k] + ch + s * 8);
        float v[24];
#pragma unroll
        for (int j = 0; j < 24; j++) v[j] = 0.f;
#pragma unroll
        for (int k = 0; k < 4; k++) {
            float wt = sw[k];
#pragma unroll
            for (int j = 0; j < 24; j++) v[j] += wt * bf2f((u16)pc[k][j >> 3][j & 7]);
        }
#pragma unroll
        for (int s = 0; s < 3; s++) {
            s16x8 ov;
#pragma unroll
            for (int e = 0; e < 8; e++) ov[e] = (short)f2bf(v[s * 8 + e]);
            *(s16x8*)&As[mi * 200 + ch + s * 8] = ov;
        }
        asm volatile("s_waitcnt vmcnt(0)" ::: "memory");
        __syncthreads();
    }

    for (int p = 0; p < 9; p++) {
        // --- issue next-tap corner loads early (hide under MFMA) ---
        s16x8 nc[4][3];
        if (p < 8) {
            const int* si = sidx[mi][p + 1];
#pragma unroll
            for (int k = 0; k < 4; k++)
#pragma unroll
                for (int s = 0; s < 3; s++)
                    nc[k][s] = *(const s16x8*)(xn + si[k] + ch + s * 8);
        }
        // --- MFMA: 6 k-steps from LDS (A stride-200, B XOR-swizzled) ---
#pragma unroll
        for (int kk = 0; kk < 6; kk++) {
            int kb = kk * 32 + kb0;
            s16x8 af[2], bfr[3];
#pragma unroll
            for (int i = 0; i < 2; i++)
                af[i] = *(const s16x8*)&As[(wm * 32 + i * 16 + (lane & 15)) * 200 + kb];
#pragma unroll
            for (int j = 0; j < 3; j++)
                bfr[j] = *(const s16x8*)&Bs[orow[j] + (kb ^ oxr[j])];
#pragma unroll
            for (int i = 0; i < 2; i++)
#pragma unroll
                for (int j = 0; j < 3; j++)
                    acc[i][j] = __builtin_amdgcn_mfma_f32_16x16x32_bf16(af[i], bfr[j], acc[i][j], 0, 0, 0);
        }
        if (p < 8) {
            __syncthreads();                // all waves done reading As/Bs
            // --- stage B tap p+1 (coalesced, latency hides under weighting) ---
            const u16* bsrc = wdT + (size_t)(p + 1) * 36864;
#pragma unroll
            for (int i2 = 0; i2 < 9; i2++) {
                int jc = wv + 8 * i2;
                gll16(bsrc + jc * 512 + lane * 8, Bs + jc * 512);
            }
            // --- weight corners -> As ---
            const float* sw = swt[mi][p + 1];
            float v[24];
#pragma unroll
            for (int j = 0; j < 24; j++) v[j] = 0.f;
#pragma unroll
            for (int k = 0; k < 4; k++) {
                float wt = sw[k];
#pragma unroll
                for (int j = 0; j < 24; j++) v[j] += wt * bf2f((u16)nc[k][j >> 3][j & 7]);
            }
#pragma unroll
            for (int s = 0; s < 3; s++) {
                s16x8 ov;
#pragma unroll
                for (int e = 0; e < 8; e++) ov[e] = (short)f2bf(v[s * 8 + e]);
                *(s16x8*)&As[mi * 200 + ch + s * 8] = ov;
            }
            asm volatile("s_waitcnt vmcnt(0)" ::: "memory");
            __syncthreads();                // staged B + As visible
        }
    }
    int col = lane & 15;
#pragma unroll
    for (int i = 0; i < 2; i++)
#pragma unroll
        for (int j = 0; j < 3; j++) {
            int mm = m0 + wm * 32 + i * 16 + (lane >> 4) * 4;
            int nn = wn * 48 + j * 16 + col;
#pragma unroll
            for (int r = 0; r < 4; r++)
                qt[(size_t)(mm + r) * 192 + nn] = f2bf(acc[i][j][r]);
        }
}

// ---------------------------------------------------------------------------
// templated bf16 MFMA GEMM: C[M,N] = A[M,K] * B^T[N,K], m97-style staging
// (single-buffer; the R9 2-phase dbuf variant regressed and was reverted).
// EP: 2 = +bias,gelu -> bf16
//     4 = +x residual (NCHW) -> xs2 fp32 AND fused LN2 -> h1 bf16 (needs BN==ldc)
//     5 = +bias + xs2 -> out fp32 NCHW transposed (fused final)
//     6 = bf16 store + fused l2norm col sums (atomicAdd to out2)
// ---------------------------------------------------------------------------
template<int BM, int BN, int WM, int WN, int EP>
__global__ __launch_bounds__((BM / WM) * (BN / WN) * 64)
void gemm_bt(const u16* __restrict__ A, int lda,
             const u16* __restrict__ B, int ldb, int bstride,
             void* __restrict__ out, int ldc,
             const float* __restrict__ ex1, int K,
             const float* __restrict__ ex2,
             const float* __restrict__ exg, const float* __restrict__ exb,
             void* __restrict__ out2)
{
    constexpr int BK = 32;
    constexpr int WAVES_M = BM / WM, WAVES_N = BN / WN, NW = WAVES_M * WAVES_N;
    constexpr int TM = WM / 16, TN = WN / 16;
    constexpr int NLA = BM / 16, NLB = BN / 16;   // 1KB global_load_lds chunks
    __shared__ u16 As[BM * BK];
    __shared__ u16 Bs[BN * BK];
    int tid = threadIdx.x;
    int lane = tid & 63, wv = tid >> 6;
    int wm = wv % WAVES_M, wn = wv / WAVES_M;
    int m0 = blockIdx.x * BM, n0 = blockIdx.y * BN;
    const u16* Bp = B + (size_t)(m0 >> 12) * bstride;
    f32x4 acc[TM][TN];
#pragma unroll
    for (int i = 0; i < TM; i++)
#pragma unroll
        for (int j = 0; j < TN; j++) {
            acc[i][j][0] = 0.f; acc[i][j][1] = 0.f; acc[i][j][2] = 0.f; acc[i][j][3] = 0.f;
        }
    int arow_l = lane >> 2;
    int acol_l = (lane & 3) * 8;
    for (int k0 = 0; k0 < K; k0 += BK) {
#pragma unroll 1
        for (int j = wv; j < NLA + NLB; j += NW) {
            if (j < NLA) {
                int row = j * 16 + arow_l;
                gll16(A + (size_t)(m0 + row) * lda + k0 + acol_l, As + j * 512);
            } else {
                int row = (j - NLA) * 16 + arow_l;
                gll16(Bp + (size_t)(n0 + row) * ldb + k0 + acol_l, Bs + (j - NLA) * 512);
            }
        }
        asm volatile("s_waitcnt vmcnt(0)" ::: "memory");
        __syncthreads();
        s16x8 af[TM], bfr[TN];
#pragma unroll
        for (int i = 0; i < TM; i++)
            af[i] = *(const s16x8*)&As[(wm * WM + i * 16 + (lane & 15)) * BK + (lane >> 4) * 8];
#pragma unroll
        for (int j = 0; j < TN; j++)
            bfr[j] = *(const s16x8*)&Bs[(wn * WN + j * 16 + (lane & 15)) * BK + (lane >> 4) * 8];
#pragma unroll
        for (int i = 0; i < TM; i++)
#pragma unroll
            for (int j = 0; j < TN; j++)
                acc[i][j] = __builtin_amdgcn_mfma_f32_16x16x32_bf16(af[i], bfr[j], acc[i][j], 0, 0, 0);
        __syncthreads();
    }
    // epilogue: C row = (lane>>4)*4 + r, col = lane&15
    int col = lane & 15;
    int rg = lane >> 4;
    if constexpr (EP == 2) {
        u16* o = (u16*)out;
#pragma unroll
        for (int i = 0; i < TM; i++)
#pragma unroll
            for (int j = 0; j < TN; j++) {
                int mm = m0 + wm * WM + i * 16 + rg * 4;
                int nn = n0 + wn * WN + j * 16 + col;
                float bb = ex1[nn];
#pragma unroll
                for (int r = 0; r < 4; r++) {
                    float v = acc[i][j][r] + bb;
                    o[(size_t)(mm + r) * ldc + nn] = f2bf(0.5f * v * (1.f + erff(v * 0.70710678118654752f)));
                }
            }
    } else if constexpr (EP == 4) {
        // v = acc + x residual; full-row LN (BN == ldc); write xs2 fp32 + h1 bf16
        __shared__ float lnA[BM][WAVES_N];  // row sums per wn-slice
        __shared__ float lnB[BM][WAVES_N];  // row sumsq per wn-slice
        float v[TM][TN][4];
        float sr[TM][4], sq[TM][4];
#pragma unroll
        for (int i = 0; i < TM; i++)
#pragma unroll
            for (int r = 0; r < 4; r++) { sr[i][r] = 0.f; sq[i][r] = 0.f; }
#pragma unroll
        for (int i = 0; i < TM; i++) {
            int mm = m0 + wm * WM + i * 16 + rg * 4;
#pragma unroll
            for (int j = 0; j < TN; j++) {
                int nn = n0 + wn * WN + j * 16 + col;
                const float* xr = ex1 + (size_t)(mm >> 12) * 786432 + (size_t)nn * 4096 + (mm & 4095);
#pragma unroll
                for (int r = 0; r < 4; r++) {
                    float vv = acc[i][j][r] + xr[r];
                    v[i][j][r] = vv;
                    sr[i][r] += vv; sq[i][r] += vv * vv;
                }
            }
        }
#pragma unroll
        for (int i = 0; i < TM; i++)
#pragma unroll
            for (int r = 0; r < 4; r++)
#pragma unroll
                for (int sh = 1; sh < 16; sh <<= 1) {
                    sr[i][r] += __shfl_xor(sr[i][r], sh);
                    sq[i][r] += __shfl_xor(sq[i][r], sh);
                }
        if (col == 0) {
#pragma unroll
            for (int i = 0; i < TM; i++)
#pragma unroll
                for (int r = 0; r < 4; r++) {
                    int row = wm * WM + i * 16 + rg * 4 + r;
                    lnA[row][wn] = sr[i][r];
                    lnB[row][wn] = sq[i][r];
                }
        }
        __syncthreads();
        float* oxs = (float*)out;
        u16* oh = (u16*)out2;
#pragma unroll
        for (int i = 0; i < TM; i++) {
            int mm = m0 + wm * WM + i * 16 + rg * 4;
#pragma unroll
            for (int r = 0; r < 4; r++) {
                int row = wm * WM + i * 16 + rg * 4 + r;
                float tot = 0.f, tq = 0.f;
#pragma unroll
                for (int q2 = 0; q2 < WAVES_N; q2++) { tot += lnA[row][q2]; tq += lnB[row][q2]; }
                float mu = tot * (1.f / 192.f);
                float var = tq * (1.f / 192.f) - mu * mu;
                float rstd = rsqrtf(var + 1e-5f);
#pragma unroll
                for (int j = 0; j < TN; j++) {
                    int nn = n0 + wn * WN + j * 16 + col;
                    float vv = v[i][j][r];
                    oxs[(size_t)(mm + r) * ldc + nn] = vv;
                    oh[(size_t)(mm + r) * ldc + nn] = f2bf((vv - mu) * rstd * exg[nn] + exb[nn]);
                }
            }
        }
    } else if constexpr (EP == 5) {
        // out = acc + bias + xs2, written NCHW transposed (fused final)
        float* o = (float*)out;
#pragma unroll
        for (int i = 0; i < TM; i++)
#pragma unroll
            for (int j = 0; j < TN; j++) {
                int mm = m0 + wm * WM + i * 16 + rg * 4;
                int nn = n0 + wn * WN + j * 16 + col;
                float bb = ex1[nn];
                size_t obase = (size_t)(mm >> 12) * 786432 + (size_t)nn * 4096;
#pragma unroll
                for (int r = 0; r < 4; r++) {
                    float vv = acc[i][j][r] + bb + ex2[(size_t)(mm + r) * ldc + nn];
                    o[obase + ((mm + r) & 4095)] = vv;
                }
            }
    } else if constexpr (EP == 6) {
        // bf16 store + fused l2norm column sums (on rounded values = old math)
        u16* o = (u16*)out;
        float* nrm = (float*)out2;
        int bI = m0 >> 12;
#pragma unroll
        for (int j = 0; j < TN; j++) {
            float s = 0.f;
#pragma unroll
            for (int i = 0; i < TM; i++) {
                int mm = m0 + wm * WM + i * 16 + rg * 4;
                int nn = n0 + wn * WN + j * 16 + col;
#pragma unroll
                for (int r = 0; r < 4; r++) {
                    u16 hb = f2bf(acc[i][j][r]);
                    o[(size_t)(mm + r) * ldc + nn] = hb;
                    float fv = bf2f(hb);
                    s += fv * fv;
                }
            }
            s += __shfl_xor(s, 16);
            s += __shfl_xor(s, 32);
            if (rg == 0) {
                int nn = n0 + wn * WN + j * 16 + col;
                atomicAdd(&nrm[bI * 384 + nn], s);
            }
        }
    }
}

// ---------------------------------------------------------------------------
// attention logits partials: raw[bh][ch][c][d] = sum_{r in chunk} q[r][c]*k[r][d]
// non-atomic private slabs; global loads vectorized (s16x8).
// ---------------------------------------------------------------------------
__global__ __launch_bounds__(64) void attnp_kernel(const u16* __restrict__ qt,
                                                   const u16* __restrict__ kvt,
                                                   float* __restrict__ raw)
{
    __shared__ float qT[32 * 69];
    __shared__ float kT[32 * 69];
    int ch = blockIdx.x, h = blockIdx.y, b = blockIdx.z;
    int t = threadIdx.x;
    size_t base = (size_t)(b * 4096 + ch * 64);
#pragma unroll
    for (int i = 0; i < 4; i++) {
        int e = t + i * 64;                 // 0..255: 64 rows x 4 8-ch chunks
        int r = e >> 2, c8 = (e & 3) * 8;
        s16x8 qv = *(const s16x8*)(qt + (base + r) * 192 + h * 32 + c8);
        s16x8 kv = *(const s16x8*)(kvt + (base + r) * 384 + h * 32 + c8);
#pragma unroll
        for (int j = 0; j < 8; j++) {
            qT[(c8 + j) * 69 + r] = bf2f((u16)qv[j]);
            kT[(c8 + j) * 69 + r] = bf2f((u16)kv[j]);
        }
    }
    __syncthreads();
    int tc = t >> 3, td = t & 7;
    int c0 = tc * 4, d0 = td * 4;
    float acc[4][4] = {};
    for (int r = 0; r < 64; r++) {
        float qv[4], kv4[4];
#pragma unroll
        for (int u = 0; u < 4; u++) { qv[u] = qT[(c0 + u) * 69 + r]; kv4[u] = kT[(d0 + u) * 69 + r]; }
#pragma unroll
        for (int u = 0; u < 4; u++)
#pragma unroll
            for (int v = 0; v < 4; v++) acc[u][v] += qv[u] * kv4[v];
    }
    float* dst = raw + (((size_t)(b * 6 + h) * 64 + ch) * 1024);
#pragma unroll
    for (int u = 0; u < 4; u++)
#pragma unroll
        for (int v = 0; v < 4; v++)
            dst[(c0 + u) * 32 + d0 + v] = acc[u][v];
}

// ---------------------------------------------------------------------------
// fused softmax + mb: sums the 64 attnp partials, k-norm + temperature folded,
// softmax over d, v-norm folded; att2 kept in LDS; then
// Mb[b][o2][h*32+d] = sum_c w_proj[o2][h*32+c] * att2[c][d] (same fp32 order
// as the old mb_kernel). One block per (b,h).
// ---------------------------------------------------------------------------
__global__ __launch_bounds__(1024) void attnfin_kernel(const float* __restrict__ raw,
                                                       const float* __restrict__ norm2,
                                                       const float* __restrict__ temp,
                                                       const float* __restrict__ wproj,
                                                       u16* __restrict__ Mb)
{
    int h = blockIdx.x, b = blockIdx.y;
    int t = threadIdx.x;
    int c = t >> 5, d = t & 31;
    __shared__ float invk[32], invv[32];
    __shared__ float attL[32][33];
    if (t < 32)       invk[t] = 1.f / fmaxf(sqrtf(norm2[b * 384 + h * 32 + t]), 1e-12f);
    else if (t < 64)  invv[t - 32] = 1.f / fmaxf(sqrtf(norm2[b * 384 + 192 + h * 32 + (t - 32)]), 1e-12f);
    __syncthreads();
    float T = temp[h];
    const float* pr = raw + (size_t)(b * 6 + h) * 65536 + c * 32 + d;
    float v = 0.f;
#pragma unroll
    for (int ch = 0; ch < 64; ch++) v += pr[ch * 1024];
    v *= invk[d] * T;
    float mx = v;
    for (int s = 16; s > 0; s >>= 1) mx = fmaxf(mx, __shfl_xor(mx, s, 32));
    float e = expf(v - mx);
    float sm = e;
    for (int s = 16; s > 0; s >>= 1) sm += __shfl_xor(sm, s, 32);
    attL[c][d] = (e / sm) * invv[d];
    __syncthreads();
    // mb phase: 192 x 32 outputs, 6 per thread
#pragma unroll
    for (int i2 = 0; i2 < 6; i2++) {
        int i = t + i2 * 1024;
        int o2 = i >> 5, dd = i & 31;
        float s = 0.f;
#pragma unroll
        for (int c2 = 0; c2 < 32; c2++)
            s += wproj[o2 * 192 + h * 32 + c2] * attL[c2][dd];
        Mb[((size_t)b * 192 + o2) * 192 + h * 32 + dd] = f2bf(s);
    }
}

// ---------------------------------------------------------------------------
extern "C" void kernel_launch(void* const* d_in, const int* in_sizes, int n_in,
                              void* d_out, int out_size, void* d_ws, size_t ws_size,
                              hipStream_t stream)
{
    const float* x      = (const float*)d_in[0];
    const float* gamma1 = (const float*)d_in[1];
    const float* beta1  = (const float*)d_in[2];
    const float* gamma2 = (const float*)d_in[3];
    const float* beta2  = (const float*)d_in[4];
    const float* temp   = (const float*)d_in[5];
    const float* w_qkv  = (const float*)d_in[6];
    const float* w_proj = (const float*)d_in[7];
    const float* w_p    = (const float*)d_in[8];
    const float* b_p    = (const float*)d_in[9];
    const float* w_d    = (const float*)d_in[10];
    const float* w_fc1  = (const float*)d_in[11];
    const float* b_fc1  = (const float*)d_in[12];
    const float* w_fc2  = (const float*)d_in[13];
    const float* b_fc2  = (const float*)d_in[14];
    float* out = (float*)d_out;
    char* ws = (char*)d_ws;

    u16*   xn    = (u16*)(ws + 0);                     // 6.29 MB (aliased: h1)
    float* off   = (float*)(ws + 6291456);             // 1.18 MB
    u16*   adef  = (u16*)(ws + 7471104);               // region (aliased: m1, wpT)
    u16*   wpT   = adef;                               // 110 KB, dead once offconv runs
    u16*   m1    = adef;                               // 25.2 MB
    float* araw  = (float*)(ws + 32636928);            // 6.29 MB attnp partials
    u16*   qt    = (u16*)(ws + 64094208);              // 6.29 MB
    u16*   kvt   = (u16*)(ws + 70385664);              // 12.6 MB
    float* norm2 = (float*)(ws + 82968576);            // 6 KB
    u16*   Mb    = (u16*)(ws + 83171328);              // 144 KB
    float* xs2   = (float*)(ws + 83318784);            // 12.6 MB
    u16*   h1    = xn;
    u16*   wdT   = (u16*)(ws + 95901696);
    u16*   wkvT  = (u16*)(ws + 96565248);
    u16*   wf1T  = (u16*)(ws + 96712704);
    u16*   wf2T  = (u16*)(ws + 97007616);              // end 97302528 B

    prep_kernel<<<1296, 256, 0, stream>>>(w_d, w_qkv, w_fc1, w_fc2, w_p, wdT, wkvT, wf1T, wf2T, wpT, norm2);
    ln1_kernel<<<256, 256, 0, stream>>>(x, gamma1, beta1, xn);
    offconv_kernel<<<256, 512, 0, stream>>>(xn, wpT, b_p, off);
    // fused gather + deform output conv: M=16384 K=1728 N=192, BM=64, 8 waves
    gemm_deform<<<256, 512, 0, stream>>>(xn, off, wdT, qt);
    // k,v projection + fused l2norm sums: M=16384 K=192 N=384
    // 8 waves (2M x 4N): was 4 waves -> only 6 waves/CU at grid 384; now 12.
    gemm_bt<128, 128, 64, 32, 6><<<dim3(128, 3), 512, 0, stream>>>(
        xn, 192, wkvT, 192, 0, kvt, 384, nullptr, 192, nullptr, nullptr, nullptr, norm2);
    attnp_kernel<<<dim3(64, 6, 4), 64, 0, stream>>>(qt, kvt, araw);
    // fused softmax + mb (att2 in LDS)
    attnfin_kernel<<<dim3(6, 4), 1024, 0, stream>>>(araw, norm2, temp, w_proj, Mb);
    // attn-apply + proj GEMM + x residual -> xs2 fp32, fused LN2 -> h1 bf16
    gemm_bt<64, 192, 32, 48, 4><<<dim3(256, 1), 512, 0, stream>>>(
        kvt + 192, 384, Mb, 192, 192 * 192, xs2, 192, x, 192, nullptr, gamma2, beta2, h1);
    // fc1 + gelu: M=16384 K=192 N=768
    gemm_bt<128, 128, 64, 64, 2><<<dim3(128, 6), 256, 0, stream>>>(
        h1, 192, wf1T, 192, 0, m1, 768, b_fc1, 192, nullptr, nullptr, nullptr, nullptr);
    // fc2 + bias + xs2, fused final transpose -> out NCHW fp32 (8 waves, 4M x 2N)
    gemm_bt<128, 96, 32, 48, 5><<<dim3(128, 2), 512, 0, stream>>>(
        m1, 768, wf2T, 768, 0, out, 192, b_fc2, 768, xs2, nullptr, nullptr, nullptr);
}

// Round 11
// 239.891 us; speedup vs baseline: 1.0339x; 1.0142x over previous
//
#include <hip/hip_runtime.h>
#include <math.h>

typedef unsigned short u16;
typedef unsigned int u32;
typedef short s16x8 __attribute__((ext_vector_type(8)));
typedef float f32x4 __attribute__((ext_vector_type(4)));

#define AS1 __attribute__((address_space(1)))
#define AS3 __attribute__((address_space(3)))

__device__ __forceinline__ float bf2f(u16 u) {
    union { u32 i; float f; } v; v.i = ((u32)u) << 16; return v.f;
}
__device__ __forceinline__ u16 f2bf(float f) {
    union { float f; u32 i; } v; v.f = f;
    u32 r = v.i + 0x7fffu + ((v.i >> 16) & 1u);
    return (u16)(r >> 16);
}
__device__ __forceinline__ void gll16(const u16* g, u16* l) {
    __builtin_amdgcn_global_load_lds((const AS1 u32*)g, (AS3 u32*)l, 16, 0, 0);
}

// ---------------------------------------------------------------------------
// prep: repack weights to B^T bf16 layouts for the MFMA GEMMs; zero norm2.
// wdT is TAP-MAJOR + XOR-swizzled:
//   wdT[(p*192 + o)*192 + (c ^ ((o&7)<<3))] = w_d[o][c][p]
// ---------------------------------------------------------------------------
__global__ void prep_kernel(const float* __restrict__ wd, const float* __restrict__ wqkv,
                            const float* __restrict__ wfc1, const float* __restrict__ wfc2,
                            const float* __restrict__ wp,
                            u16* __restrict__ wdT, u16* __restrict__ wkvT,
                            u16* __restrict__ wf1T, u16* __restrict__ wf2T,
                            u16* __restrict__ wpT, float* __restrict__ norm2)
{
    int i = blockIdx.x * 256 + threadIdx.x;
    if (i < 1536) norm2[i] = 0.f;           // 4 batches x 384 cols
    if (i < 331776) {                       // tap-major swizzled w_d
        int o = i / 1728, r = i % 1728;
        int p = r / 192, c = r % 192;
        int cs = c ^ ((o & 7) << 3);
        wdT[(p * 192 + o) * 192 + cs] = f2bf(wd[(o * 192 + c) * 9 + p]);
    }
    if (i < 73728) {                        // rows C..3C of w_qkv (k,v only)
        int o = i / 192, c = i % 192;
        wkvT[i] = f2bf(wqkv[(192 + o) * 192 + c]);
    }
    if (i < 147456) {
        int n = i / 192, c = i % 192;       // w_fc1 (192,768) -> [768][192]
        wf1T[i] = f2bf(wfc1[c * 768 + n]);
        int n2 = i / 768, hh = i % 768;     // w_fc2 (768,192) -> [192][768]
        wf2T[i] = f2bf(wfc2[hh * 192 + n2]);
    }
    if (i < 31104) {                        // w_pT[n][p*192+c] = w_p[n][c][p], pad to 32 rows
        int n = i / 1728, r = i % 1728;
        int p = r / 192, c = r % 192;
        wpT[i] = f2bf(wp[(n * 192 + c) * 9 + p]);
    } else if (i < 55296) {
        wpT[i] = 0;
    }
}

// ---------------------------------------------------------------------------
// LN1: x NCHW fp32 -> xn token-major bf16 [16384][192]; x read once (LDS stage)
// ---------------------------------------------------------------------------
__global__ __launch_bounds__(256) void ln1_kernel(const float* __restrict__ x,
                                                  const float* __restrict__ g,
                                                  const float* __restrict__ be,
                                                  u16* __restrict__ xn)
{
    __shared__ float red0[256], red1[256];
    __shared__ float mu_s[64], rs_s[64];
    __shared__ float xt[64 * 193];          // fp32 stage, stride 193 = conflict-free
    __shared__ u16 tile[64 * 194];          // bf16 out, stride 194 (97 dwords)
    int t = threadIdx.x, tl = t & 63, cg = t >> 6;
    int m0 = blockIdx.x * 64;
    int b = m0 >> 12, hw0 = m0 & 4095;
    const float* xb = x + (size_t)b * 786432 + hw0 + tl;
    float s = 0.f, s2 = 0.f;
    for (int cc = cg; cc < 192; cc += 4) {
        float v = xb[cc * 4096];
        xt[tl * 193 + cc] = v;
        s += v; s2 += v * v;
    }
    red0[t] = s; red1[t] = s2;
    __syncthreads();
    if (t < 64) {
        float a = red0[t] + red0[64 + t] + red0[128 + t] + red0[192 + t];
        float q = red1[t] + red1[64 + t] + red1[128 + t] + red1[192 + t];
        float mu = a * (1.f / 192.f);
        float var = q * (1.f / 192.f) - mu * mu;
        mu_s[t] = mu; rs_s[t] = rsqrtf(var + 1e-5f);
    }
    __syncthreads();
    float mu = mu_s[tl], rs = rs_s[tl];
    for (int cc = cg; cc < 192; cc += 4) {
        float v = (xt[tl * 193 + cc] - mu) * rs * g[cc] + be[cc];
        tile[tl * 194 + cc] = f2bf(v);
    }
    __syncthreads();
    u32* dst = (u32*)(xn + (size_t)m0 * 192);
    for (int i = t; i < 64 * 96; i += 256) {
        int r = i / 96, c2 = i % 96;
        dst[i] = *(const u32*)&tile[r * 194 + c2 * 2];
    }
}

// ---------------------------------------------------------------------------
// offset conv as direct MFMA conv: one block per (b,h) row, BM=64 (w axis),
// N=32 (18 padded), K = 9 taps x 192 ch. 8 waves (4M x 2N).
// ---------------------------------------------------------------------------
__global__ __launch_bounds__(512) void offconv_kernel(const u16* __restrict__ xn,
                                                      const u16* __restrict__ wpT,
                                                      const float* __restrict__ bp,
                                                      float* __restrict__ off)
{
    __shared__ u16 As[64 * 200];            // stride 200: rows rotate 4 banks
    __shared__ u16 Bs[32 * 200];
    int bh = blockIdx.x;
    int b = bh >> 6, h = bh & 63;
    int t = threadIdx.x;
    int lane = t & 63, wv = t >> 6;
    int wm = wv & 3, wn = wv >> 2;          // 4 M-waves x 2 N-waves
    f32x4 acc;
    acc[0] = 0.f; acc[1] = 0.f; acc[2] = 0.f; acc[3] = 0.f;
    int r = t >> 3, cq = (t & 7) * 24;      // 8 threads per A row, 24 ch each
    for (int p = 0; p < 9; p++) {
        int dh = p / 3 - 1, dw = p % 3 - 1;
        int hr = h + dh, wr = r + dw;
        bool valid = (hr >= 0) && (hr < 64) && (wr >= 0) && (wr < 64);
        const u16* src = xn + ((size_t)(b * 4096 + hr * 64 + wr)) * 192 + cq;
#pragma unroll
        for (int j = 0; j < 3; j++) {
            s16x8 v = {0, 0, 0, 0, 0, 0, 0, 0};
            if (valid) v = *(const s16x8*)(src + j * 8);
            *(s16x8*)&As[r * 200 + cq + j * 8] = v;
        }
#pragma unroll
        for (int i = 0; i < 2; i++) {
            int q = t + i * 512;
            if (q < 768) {
                int n = q / 24, c8 = q % 24;
                *(s16x8*)&Bs[n * 200 + c8 * 8] =
                    *(const s16x8*)(wpT + n * 1728 + p * 192 + c8 * 8);
            }
        }
        __syncthreads();
#pragma unroll
        for (int kc = 0; kc < 6; kc++) {
            s16x8 af = *(const s16x8*)&As[(wm * 16 + (lane & 15)) * 200 + kc * 32 + (lane >> 4) * 8];
            s16x8 b0 = *(const s16x8*)&Bs[(wn * 16 + (lane & 15)) * 200 + kc * 32 + (lane >> 4) * 8];
            acc = __builtin_amdgcn_mfma_f32_16x16x32_bf16(af, b0, acc, 0, 0, 0);
        }
        __syncthreads();
    }
    int col = lane & 15;
    int n = wn * 16 + col;
    int wbase = wm * 16 + (lane >> 4) * 4;
    if (n < 18) {
        float bb = bp[n];
#pragma unroll
        for (int rr = 0; rr < 4; rr++) {
            int w = wbase + rr;
            off[((size_t)(b * 4096 + h * 64 + w)) * 18 + n] = acc[rr] + bb;
        }
    }
}

// ---------------------------------------------------------------------------
// fused bilinear-gather + deform output conv GEMM. BM=64, 8 waves, B staged
// once per tap into LDS from tap-major pre-swizzled wdT. (R3 structure.)
// ---------------------------------------------------------------------------
__global__ __launch_bounds__(512, 2) void gemm_deform(const u16* __restrict__ xn,
                                                      const float* __restrict__ off,
                                                      const u16* __restrict__ wdT,
                                                      u16* __restrict__ qt)
{
    __shared__ u16 As[64 * 200];            // [token][ch], stride 200 rotates banks
    __shared__ u16 Bs[192 * 192];           // per-tap B panel, XOR-swizzled cols
    __shared__ int sidx[64][9][4];
    __shared__ float swt[64][9][4];
    int t = threadIdx.x, lane = t & 63, wv = t >> 6;
    int wm = wv & 1, wn = wv >> 1;          // 2 M-waves x 4 N-waves
    int m0 = blockIdx.x * 64;
    int b = m0 >> 12;
    // --- precompute bilinear corners for 64 tokens x 9 points ---
    for (int i = t; i < 576; i += 512) {
        int mi = i / 9, p = i % 9;
        int m = m0 + mi;
        int hw = m & 4095;
        int h = hw >> 6, w = hw & 63;
        float ox = off[(size_t)m * 18 + p];
        float oy = off[(size_t)m * 18 + 9 + p];
        float px = ox + (float)(h + 1) + (float)(p / 3 - 1);
        float py = oy + (float)(w + 1) + (float)(p % 3 - 1);
        float fx = floorf(px), fy = floorf(py);
        float qlx = fminf(fmaxf(fx, 0.f), 65.f);
        float qly = fminf(fmaxf(fy, 0.f), 65.f);
        float qrx = fminf(fmaxf(fx + 1.f, 0.f), 65.f);
        float qry = fminf(fmaxf(fy + 1.f, 0.f), 65.f);
        float pxc = fminf(fmaxf(px, 0.f), 65.f);
        float pyc = fminf(fmaxf(py, 0.f), 65.f);
        float gxl = 1.f + (qlx - pxc), gxr = 1.f - (qrx - pxc);
        float gyl = 1.f + (qly - pyc), gyr = 1.f - (qry - pyc);
        int xl = (int)qlx, xr = (int)qrx, yl = (int)qly, yr = (int)qry;
        int cx[4] = {xl, xr, xl, xr};
        int cy[4] = {yl, yr, yr, yl};
        float cw[4] = {gxl * gyl, gxr * gyr, gxl * gyr, gxr * gyl};
#pragma unroll
        for (int k = 0; k < 4; k++) {
            bool ok = (cx[k] >= 1) && (cx[k] <= 64) && (cy[k] >= 1) && (cy[k] <= 64);
            sidx[mi][p][k] = ok ? (b * 4096 + (cx[k] - 1) * 64 + (cy[k] - 1)) * 192 : 0;
            swt[mi][p][k] = ok ? cw[k] : 0.f;
        }
    }
    __syncthreads();
    f32x4 acc[2][3];
#pragma unroll
    for (int i = 0; i < 2; i++)
#pragma unroll
        for (int j = 0; j < 3; j++) {
            acc[i][j][0] = 0.f; acc[i][j][1] = 0.f; acc[i][j][2] = 0.f; acc[i][j][3] = 0.f;
        }
    // gather: thread owns token mi = t>>3, 24-channel strip ch
    int mi = t >> 3, ch = (t & 7) * 24;
    // B-frag row constants (per wave)
    int orow[3], oxr[3];
#pragma unroll
    for (int j = 0; j < 3; j++) {
        int o = wn * 48 + j * 16 + (lane & 15);
        orow[j] = o * 192;
        oxr[j] = (o & 7) << 3;
    }
    int kb0 = (lane >> 4) * 8;

    // --- prologue: stage B tap0, gather tap0 -> As ---
    {
        const u16* bsrc = wdT;              // tap 0 slice
#pragma unroll
        for (int i2 = 0; i2 < 9; i2++) {
            int jc = wv + 8 * i2;
            gll16(bsrc + jc * 512 + lane * 8, Bs + jc * 512);
        }
        const int*   si = sidx[mi][0];
        const float* sw = swt[mi][0];
        s16x8 pc[4][3];
#pragma unroll
        for (int k = 0; k < 4; k++)
#pragma unroll
            for (int s = 0; s < 3; s++)
                pc[k][s] = *(const s16x8*)(xn + si[k] + ch + s * 8);
        float v[24];
#pragma unroll
        for (int j = 0; j < 24; j++) v[j] = 0.f;
#pragma unroll
        for (int k = 0; k < 4; k++) {
            float wt = sw[k];
#pragma unroll
            for (int j = 0; j < 24; j++) v[j] += wt * bf2f((u16)pc[k][j >> 3][j & 7]);
        }
#pragma unroll
        for (int s = 0; s < 3; s++) {
            s16x8 ov;
#pragma unroll
            for (int e = 0; e < 8; e++) ov[e] = (short)f2bf(v[s * 8 + e]);
            *(s16x8*)&As[mi * 200 + ch + s * 8] = ov;
        }
        asm volatile("s_waitcnt vmcnt(0)" ::: "memory");
        __syncthreads();
    }

    for (int p = 0; p < 9; p++) {
        // --- issue next-tap corner loads early (hide under MFMA) ---
        s16x8 nc[4][3];
        if (p < 8) {
            const int* si = sidx[mi][p + 1];
#pragma unroll
            for (int k = 0; k < 4; k++)
#pragma unroll
                for (int s = 0; s < 3; s++)
                    nc[k][s] = *(const s16x8*)(xn + si[k] + ch + s * 8);
        }
        // --- MFMA: 6 k-steps from LDS (A stride-200, B XOR-swizzled) ---
#pragma unroll
        for (int kk = 0; kk < 6; kk++) {
            int kb = kk * 32 + kb0;
            s16x8 af[2], bfr[3];
#pragma unroll
            for (int i = 0; i < 2; i++)
                af[i] = *(const s16x8*)&As[(wm * 32 + i * 16 + (lane & 15)) * 200 + kb];
#pragma unroll
            for (int j = 0; j < 3; j++)
                bfr[j] = *(const s16x8*)&Bs[orow[j] + (kb ^ oxr[j])];
#pragma unroll
            for (int i = 0; i < 2; i++)
#pragma unroll
                for (int j = 0; j < 3; j++)
                    acc[i][j] = __builtin_amdgcn_mfma_f32_16x16x32_bf16(af[i], bfr[j], acc[i][j], 0, 0, 0);
        }
        if (p < 8) {
            __syncthreads();                // all waves done reading As/Bs
            // --- stage B tap p+1 (coalesced, latency hides under weighting) ---
            const u16* bsrc = wdT + (size_t)(p + 1) * 36864;
#pragma unroll
            for (int i2 = 0; i2 < 9; i2++) {
                int jc = wv + 8 * i2;
                gll16(bsrc + jc * 512 + lane * 8, Bs + jc * 512);
            }
            // --- weight corners -> As ---
            const float* sw = swt[mi][p + 1];
            float v[24];
#pragma unroll
            for (int j = 0; j < 24; j++) v[j] = 0.f;
#pragma unroll
            for (int k = 0; k < 4; k++) {
                float wt = sw[k];
#pragma unroll
                for (int j = 0; j < 24; j++) v[j] += wt * bf2f((u16)nc[k][j >> 3][j & 7]);
            }
#pragma unroll
            for (int s = 0; s < 3; s++) {
                s16x8 ov;
#pragma unroll
                for (int e = 0; e < 8; e++) ov[e] = (short)f2bf(v[s * 8 + e]);
                *(s16x8*)&As[mi * 200 + ch + s * 8] = ov;
            }
            asm volatile("s_waitcnt vmcnt(0)" ::: "memory");
            __syncthreads();                // staged B + As visible
        }
    }
    int col = lane & 15;
#pragma unroll
    for (int i = 0; i < 2; i++)
#pragma unroll
        for (int j = 0; j < 3; j++) {
            int mm = m0 + wm * 32 + i * 16 + (lane >> 4) * 4;
            int nn = wn * 48 + j * 16 + col;
#pragma unroll
            for (int r = 0; r < 4; r++)
                qt[(size_t)(mm + r) * 192 + nn] = f2bf(acc[i][j][r]);
        }
}

// ---------------------------------------------------------------------------
// templated bf16 MFMA GEMM: C[M,N] = A[M,K] * B^T[N,K].
// KS = K-sub-tiles (BK=32 each) staged per drain: ONE vmcnt(0)+barrier pair
// per KS k-steps (was per step -- m233: stage+drain+barrier dominated).
// Each sub-tile keeps the proven conflict-free [rows][32] LDS layout.
// EP: 2 = +bias,gelu -> bf16
//     4 = +x residual (NCHW) -> xs2 fp32 AND fused LN2 -> h1 bf16 (needs BN==ldc)
//     5 = +bias + xs2 -> out fp32 NCHW transposed (fused final)
//     6 = bf16 store + fused l2norm col sums (atomicAdd to out2)
// ---------------------------------------------------------------------------
template<int BM, int BN, int WM, int WN, int KS, int EP>
__global__ __launch_bounds__((BM / WM) * (BN / WN) * 64)
void gemm_bt(const u16* __restrict__ A, int lda,
             const u16* __restrict__ B, int ldb, int bstride,
             void* __restrict__ out, int ldc,
             const float* __restrict__ ex1, int K,
             const float* __restrict__ ex2,
             const float* __restrict__ exg, const float* __restrict__ exb,
             void* __restrict__ out2)
{
    constexpr int BK = 32;
    constexpr int WAVES_M = BM / WM, WAVES_N = BN / WN, NW = WAVES_M * WAVES_N;
    constexpr int TM = WM / 16, TN = WN / 16;
    constexpr int NLA = BM / 16, NLB = BN / 16, NCH = NLA + NLB;  // 1KB chunks per sub-tile
    __shared__ u16 As[KS][BM * BK];
    __shared__ u16 Bs[KS][BN * BK];
    int tid = threadIdx.x;
    int lane = tid & 63, wv = tid >> 6;
    int wm = wv % WAVES_M, wn = wv / WAVES_M;
    int m0 = blockIdx.x * BM, n0 = blockIdx.y * BN;
    const u16* Bp = B + (size_t)(m0 >> 12) * bstride;
    f32x4 acc[TM][TN];
#pragma unroll
    for (int i = 0; i < TM; i++)
#pragma unroll
        for (int j = 0; j < TN; j++) {
            acc[i][j][0] = 0.f; acc[i][j][1] = 0.f; acc[i][j][2] = 0.f; acc[i][j][3] = 0.f;
        }
    int arow_l = lane >> 2;
    int acol_l = (lane & 3) * 8;
    for (int k0 = 0; k0 < K; k0 += KS * BK) {
        // --- stage KS sub-tiles, one drain for all of them ---
#pragma unroll 1
        for (int c = wv; c < KS * NCH; c += NW) {
            int kk = c / NCH, j = c % NCH;
            int kc = k0 + kk * BK;
            if (j < NLA) {
                int row = j * 16 + arow_l;
                gll16(A + (size_t)(m0 + row) * lda + kc + acol_l, As[kk] + j * 512);
            } else {
                int row = (j - NLA) * 16 + arow_l;
                gll16(Bp + (size_t)(n0 + row) * ldb + kc + acol_l, Bs[kk] + (j - NLA) * 512);
            }
        }
        asm volatile("s_waitcnt vmcnt(0)" ::: "memory");
        __syncthreads();
        // --- KS k-steps of pure LDS->MFMA, no barriers between ---
#pragma unroll
        for (int kk = 0; kk < KS; kk++) {
            s16x8 af[TM], bfr[TN];
#pragma unroll
            for (int i = 0; i < TM; i++)
                af[i] = *(const s16x8*)&As[kk][(wm * WM + i * 16 + (lane & 15)) * BK + (lane >> 4) * 8];
#pragma unroll
            for (int j = 0; j < TN; j++)
                bfr[j] = *(const s16x8*)&Bs[kk][(wn * WN + j * 16 + (lane & 15)) * BK + (lane >> 4) * 8];
#pragma unroll
            for (int i = 0; i < TM; i++)
#pragma unroll
                for (int j = 0; j < TN; j++)
                    acc[i][j] = __builtin_amdgcn_mfma_f32_16x16x32_bf16(af[i], bfr[j], acc[i][j], 0, 0, 0);
        }
        __syncthreads();
    }
    // epilogue: C row = (lane>>4)*4 + r, col = lane&15
    int col = lane & 15;
    int rg = lane >> 4;
    if constexpr (EP == 2) {
        u16* o = (u16*)out;
#pragma unroll
        for (int i = 0; i < TM; i++)
#pragma unroll
            for (int j = 0; j < TN; j++) {
                int mm = m0 + wm * WM + i * 16 + rg * 4;
                int nn = n0 + wn * WN + j * 16 + col;
                float bb = ex1[nn];
#pragma unroll
                for (int r = 0; r < 4; r++) {
                    float v = acc[i][j][r] + bb;
                    o[(size_t)(mm + r) * ldc + nn] = f2bf(0.5f * v * (1.f + erff(v * 0.70710678118654752f)));
                }
            }
    } else if constexpr (EP == 4) {
        // v = acc + x residual; full-row LN (BN == ldc); write xs2 fp32 + h1 bf16
        __shared__ float lnA[BM][WAVES_N];  // row sums per wn-slice
        __shared__ float lnB[BM][WAVES_N];  // row sumsq per wn-slice
        float v[TM][TN][4];
        float sr[TM][4], sq[TM][4];
#pragma unroll
        for (int i = 0; i < TM; i++)
#pragma unroll
            for (int r = 0; r < 4; r++) { sr[i][r] = 0.f; sq[i][r] = 0.f; }
#pragma unroll
        for (int i = 0; i < TM; i++) {
            int mm = m0 + wm * WM + i * 16 + rg * 4;
#pragma unroll
            for (int j = 0; j < TN; j++) {
                int nn = n0 + wn * WN + j * 16 + col;
                const float* xr = ex1 + (size_t)(mm >> 12) * 786432 + (size_t)nn * 4096 + (mm & 4095);
#pragma unroll
                for (int r = 0; r < 4; r++) {
                    float vv = acc[i][j][r] + xr[r];
                    v[i][j][r] = vv;
                    sr[i][r] += vv; sq[i][r] += vv * vv;
                }
            }
        }
#pragma unroll
        for (int i = 0; i < TM; i++)
#pragma unroll
            for (int r = 0; r < 4; r++)
#pragma unroll
                for (int sh = 1; sh < 16; sh <<= 1) {
                    sr[i][r] += __shfl_xor(sr[i][r], sh);
                    sq[i][r] += __shfl_xor(sq[i][r], sh);
                }
        if (col == 0) {
#pragma unroll
            for (int i = 0; i < TM; i++)
#pragma unroll
                for (int r = 0; r < 4; r++) {
                    int row = wm * WM + i * 16 + rg * 4 + r;
                    lnA[row][wn] = sr[i][r];
                    lnB[row][wn] = sq[i][r];
                }
        }
        __syncthreads();
        float* oxs = (float*)out;
        u16* oh = (u16*)out2;
#pragma unroll
        for (int i = 0; i < TM; i++) {
            int mm = m0 + wm * WM + i * 16 + rg * 4;
#pragma unroll
            for (int r = 0; r < 4; r++) {
                int row = wm * WM + i * 16 + rg * 4 + r;
                float tot = 0.f, tq = 0.f;
#pragma unroll
                for (int q2 = 0; q2 < WAVES_N; q2++) { tot += lnA[row][q2]; tq += lnB[row][q2]; }
                float mu = tot * (1.f / 192.f);
                float var = tq * (1.f / 192.f) - mu * mu;
                float rstd = rsqrtf(var + 1e-5f);
#pragma unroll
                for (int j = 0; j < TN; j++) {
                    int nn = n0 + wn * WN + j * 16 + col;
                    float vv = v[i][j][r];
                    oxs[(size_t)(mm + r) * ldc + nn] = vv;
                    oh[(size_t)(mm + r) * ldc + nn] = f2bf((vv - mu) * rstd * exg[nn] + exb[nn]);
                }
            }
        }
    } else if constexpr (EP == 5) {
        // out = acc + bias + xs2, written NCHW transposed (fused final)
        float* o = (float*)out;
#pragma unroll
        for (int i = 0; i < TM; i++)
#pragma unroll
            for (int j = 0; j < TN; j++) {
                int mm = m0 + wm * WM + i * 16 + rg * 4;
                int nn = n0 + wn * WN + j * 16 + col;
                float bb = ex1[nn];
                size_t obase = (size_t)(mm >> 12) * 786432 + (size_t)nn * 4096;
#pragma unroll
                for (int r = 0; r < 4; r++) {
                    float vv = acc[i][j][r] + bb + ex2[(size_t)(mm + r) * ldc + nn];
                    o[obase + ((mm + r) & 4095)] = vv;
                }
            }
    } else if constexpr (EP == 6) {
        // bf16 store + fused l2norm column sums (on rounded values = old math)
        u16* o = (u16*)out;
        float* nrm = (float*)out2;
        int bI = m0 >> 12;
#pragma unroll
        for (int j = 0; j < TN; j++) {
            float s = 0.f;
#pragma unroll
            for (int i = 0; i < TM; i++) {
                int mm = m0 + wm * WM + i * 16 + rg * 4;
                int nn = n0 + wn * WN + j * 16 + col;
#pragma unroll
                for (int r = 0; r < 4; r++) {
                    u16 hb = f2bf(acc[i][j][r]);
                    o[(size_t)(mm + r) * ldc + nn] = hb;
                    float fv = bf2f(hb);
                    s += fv * fv;
                }
            }
            s += __shfl_xor(s, 16);
            s += __shfl_xor(s, 32);
            if (rg == 0) {
                int nn = n0 + wn * WN + j * 16 + col;
                atomicAdd(&nrm[bI * 384 + nn], s);
            }
        }
    }
}

// ---------------------------------------------------------------------------
// attention logits partials: raw[bh][ch][c][d] = sum_{r in chunk} q[r][c]*k[r][d]
// non-atomic private slabs; global loads vectorized (s16x8).
// ---------------------------------------------------------------------------
__global__ __launch_bounds__(64) void attnp_kernel(const u16* __restrict__ qt,
                                                   const u16* __restrict__ kvt,
                                                   float* __restrict__ raw)
{
    __shared__ float qT[32 * 69];
    __shared__ float kT[32 * 69];
    int ch = blockIdx.x, h = blockIdx.y, b = blockIdx.z;
    int t = threadIdx.x;
    size_t base = (size_t)(b * 4096 + ch * 64);
#pragma unroll
    for (int i = 0; i < 4; i++) {
        int e = t + i * 64;                 // 0..255: 64 rows x 4 8-ch chunks
        int r = e >> 2, c8 = (e & 3) * 8;
        s16x8 qv = *(const s16x8*)(qt + (base + r) * 192 + h * 32 + c8);
        s16x8 kv = *(const s16x8*)(kvt + (base + r) * 384 + h * 32 + c8);
#pragma unroll
        for (int j = 0; j < 8; j++) {
            qT[(c8 + j) * 69 + r] = bf2f((u16)qv[j]);
            kT[(c8 + j) * 69 + r] = bf2f((u16)kv[j]);
        }
    }
    __syncthreads();
    int tc = t >> 3, td = t & 7;
    int c0 = tc * 4, d0 = td * 4;
    float acc[4][4] = {};
    for (int r = 0; r < 64; r++) {
        float qv[4], kv4[4];
#pragma unroll
        for (int u = 0; u < 4; u++) { qv[u] = qT[(c0 + u) * 69 + r]; kv4[u] = kT[(d0 + u) * 69 + r]; }
#pragma unroll
        for (int u = 0; u < 4; u++)
#pragma unroll
            for (int v = 0; v < 4; v++) acc[u][v] += qv[u] * kv4[v];
    }
    float* dst = raw + (((size_t)(b * 6 + h) * 64 + ch) * 1024);
#pragma unroll
    for (int u = 0; u < 4; u++)
#pragma unroll
        for (int v = 0; v < 4; v++)
            dst[(c0 + u) * 32 + d0 + v] = acc[u][v];
}

// ---------------------------------------------------------------------------
// fused softmax + mb: sums the 64 attnp partials, k-norm + temperature folded,
// softmax over d, v-norm folded; att2 kept in LDS; then
// Mb[b][o2][h*32+d] = sum_c w_proj[o2][h*32+c] * att2[c][d]. One block per (b,h).
// ---------------------------------------------------------------------------
__global__ __launch_bounds__(1024) void attnfin_kernel(const float* __restrict__ raw,
                                                       const float* __restrict__ norm2,
                                                       const float* __restrict__ temp,
                                                       const float* __restrict__ wproj,
                                                       u16* __restrict__ Mb)
{
    int h = blockIdx.x, b = blockIdx.y;
    int t = threadIdx.x;
    int c = t >> 5, d = t & 31;
    __shared__ float invk[32], invv[32];
    __shared__ float attL[32][33];
    if (t < 32)       invk[t] = 1.f / fmaxf(sqrtf(norm2[b * 384 + h * 32 + t]), 1e-12f);
    else if (t < 64)  invv[t - 32] = 1.f / fmaxf(sqrtf(norm2[b * 384 + 192 + h * 32 + (t - 32)]), 1e-12f);
    __syncthreads();
    float T = temp[h];
    const float* pr = raw + (size_t)(b * 6 + h) * 65536 + c * 32 + d;
    float v = 0.f;
#pragma unroll
    for (int ch = 0; ch < 64; ch++) v += pr[ch * 1024];
    v *= invk[d] * T;
    float mx = v;
    for (int s = 16; s > 0; s >>= 1) mx = fmaxf(mx, __shfl_xor(mx, s, 32));
    float e = expf(v - mx);
    float sm = e;
    for (int s = 16; s > 0; s >>= 1) sm += __shfl_xor(sm, s, 32);
    attL[c][d] = (e / sm) * invv[d];
    __syncthreads();
    // mb phase: 192 x 32 outputs, 6 per thread
#pragma unroll
    for (int i2 = 0; i2 < 6; i2++) {
        int i = t + i2 * 1024;
        int o2 = i >> 5, dd = i & 31;
        float s = 0.f;
#pragma unroll
        for (int c2 = 0; c2 < 32; c2++)
            s += wproj[o2 * 192 + h * 32 + c2] * attL[c2][dd];
        Mb[((size_t)b * 192 + o2) * 192 + h * 32 + dd] = f2bf(s);
    }
}

// ---------------------------------------------------------------------------
extern "C" void kernel_launch(void* const* d_in, const int* in_sizes, int n_in,
                              void* d_out, int out_size, void* d_ws, size_t ws_size,
                              hipStream_t stream)
{
    const float* x      = (const float*)d_in[0];
    const float* gamma1 = (const float*)d_in[1];
    const float* beta1  = (const float*)d_in[2];
    const float* gamma2 = (const float*)d_in[3];
    const float* beta2  = (const float*)d_in[4];
    const float* temp   = (const float*)d_in[5];
    const float* w_qkv  = (const float*)d_in[6];
    const float* w_proj = (const float*)d_in[7];
    const float* w_p    = (const float*)d_in[8];
    const float* b_p    = (const float*)d_in[9];
    const float* w_d    = (const float*)d_in[10];
    const float* w_fc1  = (const float*)d_in[11];
    const float* b_fc1  = (const float*)d_in[12];
    const float* w_fc2  = (const float*)d_in[13];
    const float* b_fc2  = (const float*)d_in[14];
    float* out = (float*)d_out;
    char* ws = (char*)d_ws;

    u16*   xn    = (u16*)(ws + 0);                     // 6.29 MB (aliased: h1)
    float* off   = (float*)(ws + 6291456);             // 1.18 MB
    u16*   adef  = (u16*)(ws + 7471104);               // region (aliased: m1, wpT)
    u16*   wpT   = adef;                               // 110 KB, dead once offconv runs
    u16*   m1    = adef;                               // 25.2 MB
    float* araw  = (float*)(ws + 32636928);            // 6.29 MB attnp partials
    u16*   qt    = (u16*)(ws + 64094208);              // 6.29 MB
    u16*   kvt   = (u16*)(ws + 70385664);              // 12.6 MB
    float* norm2 = (float*)(ws + 82968576);            // 6 KB
    u16*   Mb    = (u16*)(ws + 83171328);              // 144 KB
    float* xs2   = (float*)(ws + 83318784);            // 12.6 MB
    u16*   h1    = xn;
    u16*   wdT   = (u16*)(ws + 95901696);
    u16*   wkvT  = (u16*)(ws + 96565248);
    u16*   wf1T  = (u16*)(ws + 96712704);
    u16*   wf2T  = (u16*)(ws + 97007616);              // end 97302528 B

    prep_kernel<<<1296, 256, 0, stream>>>(w_d, w_qkv, w_fc1, w_fc2, w_p, wdT, wkvT, wf1T, wf2T, wpT, norm2);
    ln1_kernel<<<256, 256, 0, stream>>>(x, gamma1, beta1, xn);
    offconv_kernel<<<256, 512, 0, stream>>>(xn, wpT, b_p, off);
    // fused gather + deform output conv: M=16384 K=1728 N=192, BM=64, 8 waves
    gemm_deform<<<256, 512, 0, stream>>>(xn, off, wdT, qt);
    // k,v projection + fused l2norm sums: M=16384 K=192 N=384 (KS=6: 1 drain)
    gemm_bt<128, 128, 64, 32, 6, 6><<<dim3(128, 3), 512, 0, stream>>>(
        xn, 192, wkvT, 192, 0, kvt, 384, nullptr, 192, nullptr, nullptr, nullptr, norm2);
    attnp_kernel<<<dim3(64, 6, 4), 64, 0, stream>>>(qt, kvt, araw);
    // fused softmax + mb (att2 in LDS)
    attnfin_kernel<<<dim3(6, 4), 1024, 0, stream>>>(araw, norm2, temp, w_proj, Mb);
    // attn-apply + proj GEMM + x residual -> xs2 fp32, fused LN2 -> h1 bf16 (KS=6)
    gemm_bt<64, 192, 32, 48, 6, 4><<<dim3(256, 1), 512, 0, stream>>>(
        kvt + 192, 384, Mb, 192, 192 * 192, xs2, 192, x, 192, nullptr, gamma2, beta2, h1);
    // fc1 + gelu: M=16384 K=192 N=768 (KS=6: 1 drain, 8 waves)
    gemm_bt<128, 128, 64, 32, 6, 2><<<dim3(128, 6), 512, 0, stream>>>(
        h1, 192, wf1T, 192, 0, m1, 768, b_fc1, 192, nullptr, nullptr, nullptr, nullptr);
    // fc2 + bias + xs2, fused final transpose -> out NCHW fp32 (KS=6: 4 drains)
    gemm_bt<128, 96, 32, 48, 6, 5><<<dim3(128, 2), 512, 0, stream>>>(
        m1, 768, wf2T, 768, 0, out, 192, b_fc2, 768, xs2, nullptr, nullptr, nullptr);
}